// Round 1
// baseline (358.822 us; speedup 1.0000x reference)
//
#include <hip/hip_runtime.h>
#include <math.h>

// Problem constants
#define BB 8
#define LL 1024
#define SS 1024
#define CC 128
#define NN 8
#define PP 256

static constexpr float EPS     = 1e-6f;
static constexpr float ONE_M_EPS = 1.0f - 1e-6f;
static constexpr float INV_T   = 1.0f / 0.07f;
static constexpr float NLL_MAX = 13.815511f;    // -log(1e-6)
static constexpr float NLL_MIN = 1.0000005e-6f; // -log(1-1e-6)

// Workspace layout (float offsets)
static constexpr size_t DOTSZ   = (size_t)BB * LL * SS;   // 8388608
static constexpr size_t OFF_LSER   = DOTSZ;               // B*L
static constexpr size_t OFF_S2RAW  = DOTSZ + 8192;        // B*L
static constexpr size_t OFF_LSEC   = DOTSZ + 16384;       // B*S
static constexpr size_t OFF_S1RAW  = DOTSZ + 24576;       // B*S
static constexpr size_t OFF_SHARP2 = DOTSZ + 32768;       // B*L
static constexpr size_t OFF_COLP   = DOTSZ + 40960;       // B*8*4*S = 262144
static constexpr size_t OFF_ACC    = OFF_COLP + (size_t)BB * 8 * 4 * SS; // B*6
static constexpr size_t OFF_ACCCL  = OFF_ACC + 48;        // 2

// Output layout (floats): sharp1[8192], cl_pos_save[1024], total, geo_pos, geo_neg, loss_sharp, loss_cl
static constexpr int OUT_CLSAVE = 8192;
static constexpr int OUT_SCAL   = 9216;

__global__ void zero_acc(float* __restrict__ ws) {
    int i = threadIdx.x;
    if (i < 50) ws[OFF_ACC + i] = 0.0f;
}

// ---------------- GEMM: dot[b,l,s] = sum_c q_geo[b,l,c]*geo_pos[b,s,c] ----------------
__global__ __launch_bounds__(256) void gemm_dot(const float* __restrict__ A,
                                                const float* __restrict__ Bm,
                                                float* __restrict__ dot) {
    int b  = blockIdx.z;
    int l0 = blockIdx.y * 128;
    int s0 = blockIdx.x * 128;
    __shared__ float As[128 * 33];
    __shared__ float Bs[128 * 33];
    int tid = threadIdx.x;
    int ty = tid >> 4, tx = tid & 15;
    float acc[8][8];
#pragma unroll
    for (int i = 0; i < 8; i++)
#pragma unroll
        for (int j = 0; j < 8; j++) acc[i][j] = 0.0f;

    const float* Ab = A + ((size_t)b * LL + l0) * CC;
    const float* Bb = Bm + ((size_t)b * SS + s0) * CC;

    for (int c0 = 0; c0 < 128; c0 += 32) {
#pragma unroll
        for (int k = 0; k < 4; k++) {
            int v = tid + k * 256;          // 0..1023 float4 slots per matrix
            int row = v >> 3;
            int cq = (v & 7) * 4;
            float4 a4 = *(const float4*)(Ab + (size_t)row * CC + c0 + cq);
            float4 b4 = *(const float4*)(Bb + (size_t)row * CC + c0 + cq);
            As[row * 33 + cq + 0] = a4.x; As[row * 33 + cq + 1] = a4.y;
            As[row * 33 + cq + 2] = a4.z; As[row * 33 + cq + 3] = a4.w;
            Bs[row * 33 + cq + 0] = b4.x; Bs[row * 33 + cq + 1] = b4.y;
            Bs[row * 33 + cq + 2] = b4.z; Bs[row * 33 + cq + 3] = b4.w;
        }
        __syncthreads();
#pragma unroll
        for (int cc = 0; cc < 32; cc++) {
            float av[8], bv[8];
#pragma unroll
            for (int i = 0; i < 8; i++) av[i] = As[(ty * 8 + i) * 33 + cc];
#pragma unroll
            for (int j = 0; j < 8; j++) bv[j] = Bs[(tx * 8 + j) * 33 + cc];
#pragma unroll
            for (int i = 0; i < 8; i++)
#pragma unroll
                for (int j = 0; j < 8; j++) acc[i][j] += av[i] * bv[j];
        }
        __syncthreads();
    }

    float* D = dot + ((size_t)b * LL + l0) * SS + s0;
#pragma unroll
    for (int i = 0; i < 8; i++) {
        float4 w0 = make_float4(acc[i][0], acc[i][1], acc[i][2], acc[i][3]);
        float4 w1 = make_float4(acc[i][4], acc[i][5], acc[i][6], acc[i][7]);
        *(float4*)(D + (size_t)(ty * 8 + i) * SS + tx * 8)     = w0;
        *(float4*)(D + (size_t)(ty * 8 + i) * SS + tx * 8 + 4) = w1;
    }
}

// ---------------- Row stats: per (b,l): LSE over s of dot/T ; max/sum/sumsq of sim2 ----------------
__global__ void row_stats(const float* __restrict__ dot, float* __restrict__ ws) {
    int row = blockIdx.x;  // b*L + l
    const float4* p = (const float4*)(dot + (size_t)row * SS);
    float4 v = p[threadIdx.x];
    float vals[4] = {v.x, v.y, v.z, v.w};
    float es = 0.0f, mx = -1e30f, sm = 0.0f, sq = 0.0f;
#pragma unroll
    for (int j = 0; j < 4; j++) {
        float d = vals[j];
        es += expf(d * INV_T);
        float s2 = 0.5f + 0.5f * d;
        mx = fmaxf(mx, s2);
        sm += s2;
        sq += s2 * s2;
    }
    for (int o = 32; o; o >>= 1) {
        es += __shfl_xor(es, o);
        mx = fmaxf(mx, __shfl_xor(mx, o));
        sm += __shfl_xor(sm, o);
        sq += __shfl_xor(sq, o);
    }
    __shared__ float sb[4][4];
    int lane = threadIdx.x & 63, wid = threadIdx.x >> 6;
    if (!lane) { sb[0][wid] = es; sb[1][wid] = mx; sb[2][wid] = sm; sb[3][wid] = sq; }
    __syncthreads();
    if (threadIdx.x == 0) {
        es = sb[0][0] + sb[0][1] + sb[0][2] + sb[0][3];
        mx = fmaxf(fmaxf(sb[1][0], sb[1][1]), fmaxf(sb[1][2], sb[1][3]));
        sm = sb[2][0] + sb[2][1] + sb[2][2] + sb[2][3];
        sq = sb[3][0] + sb[3][1] + sb[3][2] + sb[3][3];
        ws[OFF_LSER + row] = logf(es);
        float mean = sm * (1.0f / SS);
        float var = (sq - sm * sm * (1.0f / SS)) * (1.0f / (SS - 1));
        ws[OFF_S2RAW + row] = (mx - mean) / sqrtf(fmaxf(var, 1e-30f));
    }
}

// ---------------- Col stats partials over l-chunks of 128 ----------------
__global__ void col_part(const float* __restrict__ dot, float* __restrict__ ws) {
    int b = blockIdx.z, lc = blockIdx.y, sc = blockIdx.x;
    int s = sc * 256 + threadIdx.x;
    const float* base = dot + ((size_t)(b * LL + lc * 128)) * SS + s;
    float es = 0.0f, mx = -1e30f, sm = 0.0f, sq = 0.0f;
    for (int l = 0; l < 128; l++) {
        float d = base[(size_t)l * SS];
        es += expf(d * INV_T);
        float s2 = 0.5f + 0.5f * d;
        mx = fmaxf(mx, s2);
        sm += s2;
        sq += s2 * s2;
    }
    float* cp = ws + OFF_COLP + ((size_t)(b * 8 + lc) * 4) * SS + s;
    cp[0] = es; cp[SS] = mx; cp[2 * SS] = sm; cp[3 * SS] = sq;
}

__global__ void col_combine(float* __restrict__ ws) {
    int b = blockIdx.y, sc = blockIdx.x;
    int s = sc * 256 + threadIdx.x;
    float es = 0.0f, mx = -1e30f, sm = 0.0f, sq = 0.0f;
    for (int lc = 0; lc < 8; lc++) {
        const float* cp = ws + OFF_COLP + ((size_t)(b * 8 + lc) * 4) * SS + s;
        es += cp[0];
        mx = fmaxf(mx, cp[SS]);
        sm += cp[2 * SS];
        sq += cp[3 * SS];
    }
    ws[OFF_LSEC + (size_t)b * SS + s] = logf(es);
    float mean = sm * (1.0f / LL);
    float var = (sq - sm * sm * (1.0f / LL)) * (1.0f / (LL - 1));
    ws[OFF_S1RAW + (size_t)b * SS + s] = (mx - mean) / sqrtf(fmaxf(var, 1e-30f));
}

// ---------------- 16 softmaxes of length 1024: blocks 0..7 -> sharp1 (d_out), 8..15 -> sharp2 (ws) ----
__global__ void softmax16(float* __restrict__ ws, float* __restrict__ out) {
    int q = blockIdx.x;
    int b = q & 7;
    const float* src = ws + ((q < 8) ? OFF_S1RAW : OFF_S2RAW) + (size_t)b * 1024;
    float* dst = (q < 8) ? (out + (size_t)b * 1024) : (ws + OFF_SHARP2 + (size_t)b * 1024);
    float4 v = ((const float4*)src)[threadIdx.x];
    int lane = threadIdx.x & 63, wid = threadIdx.x >> 6;
    __shared__ float sb[4];
    __shared__ float red;
    float mx = fmaxf(fmaxf(v.x, v.y), fmaxf(v.z, v.w));
    for (int o = 32; o; o >>= 1) mx = fmaxf(mx, __shfl_xor(mx, o));
    if (!lane) sb[wid] = mx;
    __syncthreads();
    if (threadIdx.x == 0) red = fmaxf(fmaxf(sb[0], sb[1]), fmaxf(sb[2], sb[3]));
    __syncthreads();
    mx = red;
    float e0 = expf(v.x - mx), e1 = expf(v.y - mx), e2 = expf(v.z - mx), e3 = expf(v.w - mx);
    float sm = e0 + e1 + e2 + e3;
    for (int o = 32; o; o >>= 1) sm += __shfl_xor(sm, o);
    __syncthreads();
    if (!lane) sb[wid] = sm;
    __syncthreads();
    if (threadIdx.x == 0) red = sb[0] + sb[1] + sb[2] + sb[3];
    __syncthreads();
    float inv = 1.0f / red;
    ((float4*)dst)[threadIdx.x] = make_float4(e0 * inv, e1 * inv, e2 * inv, e3 * inv);
}

// ---------------- Main elementwise loss pass ----------------
__device__ __forceinline__ void proc_elem(float d, int lab, float lcj, float sh1j,
                                          float lr, float s2v,
                                          float& posg, float& negg, float& l1, float& l2,
                                          float& negs, int& pc) {
    float t = lr + lcj - d * (2.0f * INV_T);   // -log(conf), >= 0 analytically
    float simc = fminf(fmaxf(0.5f + 0.5f * d, EPS), ONE_M_EPS);
    if (lab == 1) {
        posg += fminf(fmaxf(t, NLL_MIN), NLL_MAX);
        float nll2 = -logf(simc);
        l1 += nll2 * sh1j;
        l2 += nll2 * s2v;
        pc++;
    } else {
        float cf = fminf(fmaxf(expf(-t), EPS), ONE_M_EPS);
        negg -= log1pf(-cf);
        negs -= log1pf(-simc);
    }
}

__global__ __launch_bounds__(256) void main_loss(const float* __restrict__ dot,
                                                 const int* __restrict__ label,
                                                 const float* __restrict__ sharp1,
                                                 float* __restrict__ ws) {
    int b = blockIdx.y;
    int l0 = blockIdx.x * 64;
    int s = threadIdx.x * 4;
    float4 lc4 = *(const float4*)(ws + OFF_LSEC + (size_t)b * 1024 + s);
    float4 sh1 = *(const float4*)(sharp1 + (size_t)b * 1024 + s);
    const float* lser = ws + OFF_LSER + (size_t)b * 1024;
    const float* sh2 = ws + OFF_SHARP2 + (size_t)b * 1024;
    float posg = 0, negg = 0, l1 = 0, l2 = 0, negs = 0;
    int pc = 0;
    for (int l = l0; l < l0 + 64; l++) {
        float lr = lser[l];
        float s2v = sh2[l];
        size_t base = ((size_t)(b * 1024 + l)) * 1024 + s;
        float4 d4 = *(const float4*)(dot + base);
        int4 lb = *(const int4*)(label + base);
        proc_elem(d4.x, lb.x, lc4.x, sh1.x, lr, s2v, posg, negg, l1, l2, negs, pc);
        proc_elem(d4.y, lb.y, lc4.y, sh1.y, lr, s2v, posg, negg, l1, l2, negs, pc);
        proc_elem(d4.z, lb.z, lc4.z, sh1.z, lr, s2v, posg, negg, l1, l2, negs, pc);
        proc_elem(d4.w, lb.w, lc4.w, sh1.w, lr, s2v, posg, negg, l1, l2, negs, pc);
    }
    float vals[6] = {posg, negg, l1, l2, negs, (float)pc};
    __shared__ float sb[6][4];
    int lane = threadIdx.x & 63, wid = threadIdx.x >> 6;
#pragma unroll
    for (int k = 0; k < 6; k++) {
        float v = vals[k];
        for (int o = 32; o; o >>= 1) v += __shfl_xor(v, o);
        if (!lane) sb[k][wid] = v;
    }
    __syncthreads();
    if (threadIdx.x < 6) {
        float r = sb[threadIdx.x][0] + sb[threadIdx.x][1] + sb[threadIdx.x][2] + sb[threadIdx.x][3];
        atomicAdd(ws + OFF_ACC + (size_t)b * 6 + threadIdx.x, r);
    }
}

// ---------------- Contrast loss (tiny) ----------------
__global__ void contrast(const float* __restrict__ q_cl, const float* __restrict__ cl_pos,
                         const int* __restrict__ idx, float* __restrict__ out,
                         float* __restrict__ ws) {
    int n = blockIdx.x;
    __shared__ float qs[128];
    __shared__ float sb[2][4];
    int in = idx[n];
    const float* q = q_cl + ((size_t)(n * PP + in)) * CC;
    if (threadIdx.x < 128) {
        qs[threadIdx.x] = q[threadIdx.x];
        // cl_pos_save = cl_pos[n, idx[n], :]
        out[OUT_CLSAVE + n * 128 + threadIdx.x] = cl_pos[((size_t)(n * PP + in)) * CC + threadIdx.x];
    }
    __syncthreads();
    float qsq = 0.0f;
#pragma unroll
    for (int c = 0; c < 128; c++) qsq += qs[c] * qs[c];
    float qn = fmaxf(sqrtf(qsq), 1e-12f);
    float pos = 0.0f, neg = 0.0f;
    for (int j = threadIdx.x; j < 2048; j += 256) {
        const float* k;
        if (j < NN) {
            int m = j;
            k = cl_pos + ((size_t)(m * PP + idx[m])) * CC;   // all_k[j<N] = sel[j]
        } else {
            int jj = j - NN;
            int m = jj / (PP - 1);
            int p = 1 + (jj - m * (PP - 1));
            if (p == idx[m]) p = 0;                           // swapped: position idx[m] holds row 0
            k = cl_pos + ((size_t)(m * PP + p)) * CC;
        }
        float dt = 0.0f, ksq = 0.0f;
#pragma unroll
        for (int c = 0; c < 128; c++) {
            float kv = k[c];
            dt += qs[c] * kv;
            ksq += kv * kv;
        }
        float kn = fmaxf(sqrtf(ksq), 1e-12f);
        float sim = 0.5f + 0.5f * (dt / (qn * kn));
        sim = fminf(fmaxf(sim, EPS), ONE_M_EPS);
        if (j == n) pos -= logf(sim);
        if (j >= NN) neg -= log1pf(-sim);
    }
    int lane = threadIdx.x & 63, wid = threadIdx.x >> 6;
    for (int o = 32; o; o >>= 1) { pos += __shfl_xor(pos, o); neg += __shfl_xor(neg, o); }
    if (!lane) { sb[0][wid] = pos; sb[1][wid] = neg; }
    __syncthreads();
    if (threadIdx.x == 0) {
        atomicAdd(ws + OFF_ACCCL + 0, sb[0][0] + sb[0][1] + sb[0][2] + sb[0][3]);
        atomicAdd(ws + OFF_ACCCL + 1, sb[1][0] + sb[1][1] + sb[1][2] + sb[1][3]);
    }
}

// ---------------- Final scalar combine ----------------
__global__ void finalize(float* __restrict__ out, const float* __restrict__ ws) {
    if (threadIdx.x != 0) return;
    float gp = 0, gn = 0, lsh = 0;
    for (int b = 0; b < 8; b++) {
        const float* a = ws + OFF_ACC + (size_t)b * 6;
        float pc = a[5];
        float nc = (float)((size_t)LL * SS) - pc;
        gp += a[0] / fmaxf(pc, 1.0f);
        gn += a[1] / fmaxf(nc, 1.0f);
        lsh += (a[2] + a[3]) * 0.5f + a[4] / fmaxf(nc, 1.0f);
    }
    gp *= 0.125f; gn *= 0.125f; lsh *= 0.125f;
    float lgeo = gp + gn;
    float lgw = (0.5f * lgeo + 0.5f * lsh) * 0.5f;
    float clp = ws[OFF_ACCCL + 0] / 8.0f;
    float cln = ws[OFF_ACCCL + 1] / (8.0f * 2040.0f);
    float lcl = (clp + cln) * 0.5f * 0.5f;
    out[OUT_SCAL + 0] = lgw + lcl;  // total
    out[OUT_SCAL + 1] = gp;         // geo_pos_loss
    out[OUT_SCAL + 2] = gn;         // geo_neg_loss
    out[OUT_SCAL + 3] = lsh;        // loss_sharp
    out[OUT_SCAL + 4] = lcl;        // loss_cl
}

extern "C" void kernel_launch(void* const* d_in, const int* in_sizes, int n_in,
                              void* d_out, int out_size, void* d_ws, size_t ws_size,
                              hipStream_t stream) {
    const float* q_geo   = (const float*)d_in[0];
    const float* q_cl    = (const float*)d_in[1];
    const float* geo_pos = (const float*)d_in[2];
    const float* cl_pos  = (const float*)d_in[3];
    const int*   label   = (const int*)d_in[4];
    const int*   idx     = (const int*)d_in[5];
    float* out = (float*)d_out;
    float* ws  = (float*)d_ws;
    float* dot = ws;

    zero_acc<<<dim3(1), dim3(64), 0, stream>>>(ws);
    gemm_dot<<<dim3(8, 8, 8), dim3(256), 0, stream>>>(q_geo, geo_pos, dot);
    row_stats<<<dim3(8192), dim3(256), 0, stream>>>(dot, ws);
    col_part<<<dim3(4, 8, 8), dim3(256), 0, stream>>>(dot, ws);
    col_combine<<<dim3(4, 8), dim3(256), 0, stream>>>(ws);
    softmax16<<<dim3(16), dim3(256), 0, stream>>>(ws, out);
    main_loss<<<dim3(16, 8), dim3(256), 0, stream>>>(dot, label, out, ws);
    contrast<<<dim3(8), dim3(256), 0, stream>>>(q_cl, cl_pos, idx, out, ws);
    finalize<<<dim3(1), dim3(64), 0, stream>>>(out, ws);
}

// Round 2
// 197.487 us; speedup vs baseline: 1.8169x; 1.8169x over previous
//
#include <hip/hip_runtime.h>
#include <math.h>

// Problem constants
#define BB 8
#define LL 1024
#define SS 1024
#define CC 128
#define NN 8
#define PP 256

static constexpr float EPS       = 1e-6f;
static constexpr float ONE_M_EPS = 1.0f - 1e-6f;
static constexpr float INV_T     = 1.0f / 0.07f;
static constexpr float NLL_MAX   = 13.815511f;    // -log(1e-6)
static constexpr float NLL_MIN   = 1.0000005e-6f; // -log(1-1e-6)

// Workspace layout (float offsets)
static constexpr size_t DOTSZ      = (size_t)BB * LL * SS;   // 8388608
static constexpr size_t OFF_LSER   = DOTSZ;                  // B*L
static constexpr size_t OFF_S2RAW  = DOTSZ + 8192;           // B*L
static constexpr size_t OFF_LSEC   = DOTSZ + 16384;          // B*S
static constexpr size_t OFF_S1RAW  = DOTSZ + 24576;          // B*S
static constexpr size_t OFF_SHARP2 = DOTSZ + 32768;          // B*L
static constexpr int    LCH        = 16;                     // l-chunks for col stats
static constexpr size_t OFF_COLP   = DOTSZ + 40960;          // B*LCH*4*S = 524288
static constexpr size_t OFF_ACC    = OFF_COLP + (size_t)BB * LCH * 4 * SS; // B*6
static constexpr size_t OFF_ACCCL  = OFF_ACC + 48;           // 2
static constexpr size_t OFF_QN     = OFF_ACC + 64;           // 8*128 normalized q_sel

// Output layout (floats): sharp1[8192], cl_pos_save[1024], total, geo_pos, geo_neg, loss_sharp, loss_cl
static constexpr int OUT_CLSAVE = 8192;
static constexpr int OUT_SCAL   = 9216;

// ---------------- Prep: zero accumulators, normalize q_sel, write cl_pos_save ----------------
__global__ __launch_bounds__(512) void prep(const float* __restrict__ q_cl,
                                            const float* __restrict__ cl_pos,
                                            const int* __restrict__ idx,
                                            float* __restrict__ out, float* __restrict__ ws) {
    int tid = threadIdx.x;
    if (tid < 50) ws[OFF_ACC + tid] = 0.0f;   // 48 geo acc + 2 contrast acc
    int n = tid >> 6, lane = tid & 63;
    int in = idx[n];
    const float* q = q_cl + ((size_t)(n * PP + in)) * CC;
    float2 qv = *(const float2*)(q + 2 * lane);
    float ss = qv.x * qv.x + qv.y * qv.y;
    for (int o = 32; o; o >>= 1) ss += __shfl_xor(ss, o);
    float inv = 1.0f / fmaxf(sqrtf(ss), 1e-12f);
    *(float2*)(ws + OFF_QN + n * 128 + 2 * lane) = make_float2(qv.x * inv, qv.y * inv);
    const float* cp = cl_pos + ((size_t)(n * PP + in)) * CC;
    float2 cv = *(const float2*)(cp + 2 * lane);
    *(float2*)(out + OUT_CLSAVE + n * 128 + 2 * lane) = cv;
}

// ---------------- GEMM: dot[b,l,s] = sum_c q_geo[b,l,c]*geo_pos[b,s,c] ----------------
__global__ __launch_bounds__(256) void gemm_dot(const float* __restrict__ A,
                                                const float* __restrict__ Bm,
                                                float* __restrict__ dot) {
    int b  = blockIdx.z;
    int l0 = blockIdx.y * 128;
    int s0 = blockIdx.x * 128;
    __shared__ float As[128 * 33];
    __shared__ float Bs[128 * 33];
    int tid = threadIdx.x;
    int ty = tid >> 4, tx = tid & 15;
    float acc[8][8];
#pragma unroll
    for (int i = 0; i < 8; i++)
#pragma unroll
        for (int j = 0; j < 8; j++) acc[i][j] = 0.0f;

    const float* Ab = A + ((size_t)b * LL + l0) * CC;
    const float* Bb = Bm + ((size_t)b * SS + s0) * CC;

    for (int c0 = 0; c0 < 128; c0 += 32) {
#pragma unroll
        for (int k = 0; k < 4; k++) {
            int v = tid + k * 256;
            int row = v >> 3;
            int cq = (v & 7) * 4;
            float4 a4 = *(const float4*)(Ab + (size_t)row * CC + c0 + cq);
            float4 b4 = *(const float4*)(Bb + (size_t)row * CC + c0 + cq);
            As[row * 33 + cq + 0] = a4.x; As[row * 33 + cq + 1] = a4.y;
            As[row * 33 + cq + 2] = a4.z; As[row * 33 + cq + 3] = a4.w;
            Bs[row * 33 + cq + 0] = b4.x; Bs[row * 33 + cq + 1] = b4.y;
            Bs[row * 33 + cq + 2] = b4.z; Bs[row * 33 + cq + 3] = b4.w;
        }
        __syncthreads();
#pragma unroll
        for (int cc = 0; cc < 32; cc++) {
            float av[8], bv[8];
#pragma unroll
            for (int i = 0; i < 8; i++) av[i] = As[(ty * 8 + i) * 33 + cc];
#pragma unroll
            for (int j = 0; j < 8; j++) bv[j] = Bs[(tx * 8 + j) * 33 + cc];
#pragma unroll
            for (int i = 0; i < 8; i++)
#pragma unroll
                for (int j = 0; j < 8; j++) acc[i][j] += av[i] * bv[j];
        }
        __syncthreads();
    }

    float* D = dot + ((size_t)b * LL + l0) * SS + s0;
#pragma unroll
    for (int i = 0; i < 8; i++) {
        float4 w0 = make_float4(acc[i][0], acc[i][1], acc[i][2], acc[i][3]);
        float4 w1 = make_float4(acc[i][4], acc[i][5], acc[i][6], acc[i][7]);
        *(float4*)(D + (size_t)(ty * 8 + i) * SS + tx * 8)     = w0;
        *(float4*)(D + (size_t)(ty * 8 + i) * SS + tx * 8 + 4) = w1;
    }
}

// ---------------- Row stats: per (b,l): LSE over s of dot/T ; max/sum/sumsq of sim2 ----------------
__global__ __launch_bounds__(256) void row_stats(const float* __restrict__ dot, float* __restrict__ ws) {
    int row = blockIdx.x;  // b*L + l
    const float4* p = (const float4*)(dot + (size_t)row * SS);
    float4 v = p[threadIdx.x];
    float vals[4] = {v.x, v.y, v.z, v.w};
    float es = 0.0f, mx = -1e30f, sm = 0.0f, sq = 0.0f;
#pragma unroll
    for (int j = 0; j < 4; j++) {
        float d = vals[j];
        es += __expf(d * INV_T);
        float s2 = 0.5f + 0.5f * d;
        mx = fmaxf(mx, s2);
        sm += s2;
        sq += s2 * s2;
    }
    for (int o = 32; o; o >>= 1) {
        es += __shfl_xor(es, o);
        mx = fmaxf(mx, __shfl_xor(mx, o));
        sm += __shfl_xor(sm, o);
        sq += __shfl_xor(sq, o);
    }
    __shared__ float sb[4][4];
    int lane = threadIdx.x & 63, wid = threadIdx.x >> 6;
    if (!lane) { sb[0][wid] = es; sb[1][wid] = mx; sb[2][wid] = sm; sb[3][wid] = sq; }
    __syncthreads();
    if (threadIdx.x == 0) {
        es = sb[0][0] + sb[0][1] + sb[0][2] + sb[0][3];
        mx = fmaxf(fmaxf(sb[1][0], sb[1][1]), fmaxf(sb[1][2], sb[1][3]));
        sm = sb[2][0] + sb[2][1] + sb[2][2] + sb[2][3];
        sq = sb[3][0] + sb[3][1] + sb[3][2] + sb[3][3];
        ws[OFF_LSER + row] = __logf(es);
        float mean = sm * (1.0f / SS);
        float var = (sq - sm * sm * (1.0f / SS)) * (1.0f / (SS - 1));
        ws[OFF_S2RAW + row] = (mx - mean) / sqrtf(fmaxf(var, 1e-30f));
    }
}

// ---------------- Col stats partials over l-chunks of 64 ----------------
__global__ __launch_bounds__(256) void col_part(const float* __restrict__ dot, float* __restrict__ ws) {
    int b = blockIdx.z, lc = blockIdx.y, sc = blockIdx.x;
    int s = sc * 256 + threadIdx.x;
    const float* base = dot + ((size_t)(b * LL + lc * (LL / LCH))) * SS + s;
    float es = 0.0f, mx = -1e30f, sm = 0.0f, sq = 0.0f;
    for (int l = 0; l < LL / LCH; l++) {
        float d = base[(size_t)l * SS];
        es += __expf(d * INV_T);
        float s2 = 0.5f + 0.5f * d;
        mx = fmaxf(mx, s2);
        sm += s2;
        sq += s2 * s2;
    }
    float* cp = ws + OFF_COLP + ((size_t)(b * LCH + lc) * 4) * SS + s;
    cp[0] = es; cp[SS] = mx; cp[2 * SS] = sm; cp[3 * SS] = sq;
}

__global__ __launch_bounds__(256) void col_combine(float* __restrict__ ws) {
    int b = blockIdx.y, sc = blockIdx.x;
    int s = sc * 256 + threadIdx.x;
    float es = 0.0f, mx = -1e30f, sm = 0.0f, sq = 0.0f;
    for (int lc = 0; lc < LCH; lc++) {
        const float* cp = ws + OFF_COLP + ((size_t)(b * LCH + lc) * 4) * SS + s;
        es += cp[0];
        mx = fmaxf(mx, cp[SS]);
        sm += cp[2 * SS];
        sq += cp[3 * SS];
    }
    ws[OFF_LSEC + (size_t)b * SS + s] = __logf(es);
    float mean = sm * (1.0f / LL);
    float var = (sq - sm * sm * (1.0f / LL)) * (1.0f / (LL - 1));
    ws[OFF_S1RAW + (size_t)b * SS + s] = (mx - mean) / sqrtf(fmaxf(var, 1e-30f));
}

// ---------------- 16 softmaxes of length 1024: blocks 0..7 -> sharp1 (d_out), 8..15 -> sharp2 (ws) ----
__global__ __launch_bounds__(256) void softmax16(float* __restrict__ ws, float* __restrict__ out) {
    int q = blockIdx.x;
    int b = q & 7;
    const float* src = ws + ((q < 8) ? OFF_S1RAW : OFF_S2RAW) + (size_t)b * 1024;
    float* dst = (q < 8) ? (out + (size_t)b * 1024) : (ws + OFF_SHARP2 + (size_t)b * 1024);
    float4 v = ((const float4*)src)[threadIdx.x];
    int lane = threadIdx.x & 63, wid = threadIdx.x >> 6;
    __shared__ float sb[4];
    __shared__ float red;
    float mx = fmaxf(fmaxf(v.x, v.y), fmaxf(v.z, v.w));
    for (int o = 32; o; o >>= 1) mx = fmaxf(mx, __shfl_xor(mx, o));
    if (!lane) sb[wid] = mx;
    __syncthreads();
    if (threadIdx.x == 0) red = fmaxf(fmaxf(sb[0], sb[1]), fmaxf(sb[2], sb[3]));
    __syncthreads();
    mx = red;
    float e0 = __expf(v.x - mx), e1 = __expf(v.y - mx), e2 = __expf(v.z - mx), e3 = __expf(v.w - mx);
    float sm = e0 + e1 + e2 + e3;
    for (int o = 32; o; o >>= 1) sm += __shfl_xor(sm, o);
    __syncthreads();
    if (!lane) sb[wid] = sm;
    __syncthreads();
    if (threadIdx.x == 0) red = sb[0] + sb[1] + sb[2] + sb[3];
    __syncthreads();
    float inv = 1.0f / red;
    ((float4*)dst)[threadIdx.x] = make_float4(e0 * inv, e1 * inv, e2 * inv, e3 * inv);
}

// ---------------- Main elementwise loss pass (branchless) ----------------
__device__ __forceinline__ void proc_elem(float d, int lab, float lcj, float sh1j,
                                          float lr, float s2v,
                                          float& posg, float& negg, float& l1, float& l2,
                                          float& negs, float& pcf) {
    float t = lr + lcj - d * (2.0f * INV_T);   // -log(conf_geo)
    float isPos = (lab == 1) ? 1.0f : 0.0f;
    float isNeg = 1.0f - isPos;
    float tp   = fminf(fmaxf(t, NLL_MIN), NLL_MAX);
    float simc = fminf(fmaxf(fmaf(0.5f, d, 0.5f), EPS), ONE_M_EPS);
    float om   = fminf(fmaxf(fmaf(-0.5f, d, 0.5f), EPS), ONE_M_EPS);   // 1-simc exactly
    float nll2 = -__logf(simc);
    float cf   = fminf(fmaxf(__expf(-t), EPS), ONE_M_EPS);
    float nllg = -__logf(1.0f - cf);
    float nlls = -__logf(om);
    posg += isPos * tp;
    l1   += isPos * nll2 * sh1j;
    l2   += isPos * nll2 * s2v;
    pcf  += isPos;
    negg += isNeg * nllg;
    negs += isNeg * nlls;
}

__global__ __launch_bounds__(256) void main_loss(const float* __restrict__ dot,
                                                 const int* __restrict__ label,
                                                 const float* __restrict__ sharp1,
                                                 float* __restrict__ ws) {
    int b = blockIdx.y;
    int l0 = blockIdx.x * 4;
    int s = threadIdx.x * 4;
    float4 lc4 = *(const float4*)(ws + OFF_LSEC + (size_t)b * 1024 + s);
    float4 sh1 = *(const float4*)(sharp1 + (size_t)b * 1024 + s);
    const float* lser = ws + OFF_LSER + (size_t)b * 1024;
    const float* sh2  = ws + OFF_SHARP2 + (size_t)b * 1024;
    float posg = 0, negg = 0, l1 = 0, l2 = 0, negs = 0, pcf = 0;
#pragma unroll
    for (int r = 0; r < 4; r++) {
        int l = l0 + r;
        float lr  = lser[l];
        float s2v = sh2[l];
        size_t base = ((size_t)(b * 1024 + l)) * 1024 + s;
        float4 d4 = *(const float4*)(dot + base);
        int4  lb  = *(const int4*)(label + base);
        proc_elem(d4.x, lb.x, lc4.x, sh1.x, lr, s2v, posg, negg, l1, l2, negs, pcf);
        proc_elem(d4.y, lb.y, lc4.y, sh1.y, lr, s2v, posg, negg, l1, l2, negs, pcf);
        proc_elem(d4.z, lb.z, lc4.z, sh1.z, lr, s2v, posg, negg, l1, l2, negs, pcf);
        proc_elem(d4.w, lb.w, lc4.w, sh1.w, lr, s2v, posg, negg, l1, l2, negs, pcf);
    }
    float vals[6] = {posg, negg, l1, l2, negs, pcf};
    __shared__ float sb[6][4];
    int lane = threadIdx.x & 63, wid = threadIdx.x >> 6;
#pragma unroll
    for (int k = 0; k < 6; k++) {
        float v = vals[k];
        for (int o = 32; o; o >>= 1) v += __shfl_xor(v, o);
        if (!lane) sb[k][wid] = v;
    }
    __syncthreads();
    if (threadIdx.x < 6) {
        float r = sb[threadIdx.x][0] + sb[threadIdx.x][1] + sb[threadIdx.x][2] + sb[threadIdx.x][3];
        atomicAdd(ws + OFF_ACC + (size_t)b * 6 + threadIdx.x, r);
    }
}

// ---------------- Contrast loss: one wave per all_k row j ----------------
__global__ __launch_bounds__(256) void contrast(const float* __restrict__ cl_pos,
                                                const int* __restrict__ idx,
                                                float* __restrict__ ws) {
    int j = blockIdx.x * 4 + (threadIdx.x >> 6);
    int lane = threadIdx.x & 63;
    int m, p;
    if (j < NN) {
        m = j; p = idx[j];                 // all_k[j<N] = cl_pos[j, idx[j]]
    } else {
        int jj = j - NN;
        m = jj / (PP - 1);
        p = 1 + (jj - m * (PP - 1));
        if (p == idx[m]) p = 0;            // swapped: position idx[m] holds original row 0
    }
    const float* k = cl_pos + ((size_t)(m * PP + p)) * CC;
    float2 kv = *(const float2*)(k + 2 * lane);
    float ksq = kv.x * kv.x + kv.y * kv.y;
    for (int o = 32; o; o >>= 1) ksq += __shfl_xor(ksq, o);
    float invkn = 1.0f / fmaxf(sqrtf(ksq), 1e-12f);
    float pos = 0.0f, neg = 0.0f;
    if (j < NN) {
        // only the diagonal element contributes (l_pos)
        const float2 qv = *(const float2*)(ws + OFF_QN + j * 128 + 2 * lane);
        float dt = qv.x * kv.x + qv.y * kv.y;
        for (int o = 32; o; o >>= 1) dt += __shfl_xor(dt, o);
        float sim = fminf(fmaxf(fmaf(0.5f * invkn, dt, 0.5f), EPS), ONE_M_EPS);
        pos = -__logf(sim);
    } else {
#pragma unroll
        for (int n = 0; n < NN; n++) {
            const float2 qv = *(const float2*)(ws + OFF_QN + n * 128 + 2 * lane);
            float dt = qv.x * kv.x + qv.y * kv.y;
            for (int o = 32; o; o >>= 1) dt += __shfl_xor(dt, o);
            float om = fminf(fmaxf(fmaf(-0.5f * invkn, dt, 0.5f), EPS), ONE_M_EPS); // 1-sim
            neg -= __logf(om);
        }
    }
    __shared__ float sb[2][4];
    int w = threadIdx.x >> 6;
    if (!lane) { sb[0][w] = pos; sb[1][w] = neg; }
    __syncthreads();
    if (threadIdx.x == 0) {
        float ps = sb[0][0] + sb[0][1] + sb[0][2] + sb[0][3];
        float ng = sb[1][0] + sb[1][1] + sb[1][2] + sb[1][3];
        if (ps != 0.0f) atomicAdd(ws + OFF_ACCCL + 0, ps);
        if (ng != 0.0f) atomicAdd(ws + OFF_ACCCL + 1, ng);
    }
}

// ---------------- Final scalar combine ----------------
__global__ void finalize(float* __restrict__ out, const float* __restrict__ ws) {
    if (threadIdx.x != 0) return;
    float gp = 0, gn = 0, lsh = 0;
    for (int b = 0; b < 8; b++) {
        const float* a = ws + OFF_ACC + (size_t)b * 6;
        float pc = a[5];
        float nc = (float)((size_t)LL * SS) - pc;
        gp += a[0] / fmaxf(pc, 1.0f);
        gn += a[1] / fmaxf(nc, 1.0f);
        lsh += (a[2] + a[3]) * 0.5f + a[4] / fmaxf(nc, 1.0f);
    }
    gp *= 0.125f; gn *= 0.125f; lsh *= 0.125f;
    float lgeo = gp + gn;
    float lgw = (0.5f * lgeo + 0.5f * lsh) * 0.5f;
    float clp = ws[OFF_ACCCL + 0] / 8.0f;
    float cln = ws[OFF_ACCCL + 1] / (8.0f * 2040.0f);
    float lcl = (clp + cln) * 0.5f * 0.5f;
    out[OUT_SCAL + 0] = lgw + lcl;  // total
    out[OUT_SCAL + 1] = gp;         // geo_pos_loss
    out[OUT_SCAL + 2] = gn;         // geo_neg_loss
    out[OUT_SCAL + 3] = lsh;        // loss_sharp
    out[OUT_SCAL + 4] = lcl;        // loss_cl
}

extern "C" void kernel_launch(void* const* d_in, const int* in_sizes, int n_in,
                              void* d_out, int out_size, void* d_ws, size_t ws_size,
                              hipStream_t stream) {
    const float* q_geo   = (const float*)d_in[0];
    const float* q_cl    = (const float*)d_in[1];
    const float* geo_pos = (const float*)d_in[2];
    const float* cl_pos  = (const float*)d_in[3];
    const int*   label   = (const int*)d_in[4];
    const int*   idx     = (const int*)d_in[5];
    float* out = (float*)d_out;
    float* ws  = (float*)d_ws;
    float* dot = ws;

    prep<<<dim3(1), dim3(512), 0, stream>>>(q_cl, cl_pos, idx, out, ws);
    gemm_dot<<<dim3(8, 8, 8), dim3(256), 0, stream>>>(q_geo, geo_pos, dot);
    row_stats<<<dim3(8192), dim3(256), 0, stream>>>(dot, ws);
    col_part<<<dim3(4, LCH, 8), dim3(256), 0, stream>>>(dot, ws);
    col_combine<<<dim3(4, 8), dim3(256), 0, stream>>>(ws);
    softmax16<<<dim3(16), dim3(256), 0, stream>>>(ws, out);
    main_loss<<<dim3(256, 8), dim3(256), 0, stream>>>(dot, label, out, ws);
    contrast<<<dim3(512), dim3(256), 0, stream>>>(cl_pos, idx, ws);
    finalize<<<dim3(1), dim3(64), 0, stream>>>(out, ws);
}

// Round 3
// 169.383 us; speedup vs baseline: 2.1184x; 1.1659x over previous
//
#include <hip/hip_runtime.h>
#include <math.h>

// Problem constants
#define BB 8
#define LL 1024
#define SS 1024
#define CC 128
#define NN 8
#define PP 256

static constexpr float EPS       = 1e-6f;
static constexpr float ONE_M_EPS = 1.0f - 1e-6f;
static constexpr float INV_T     = 1.0f / 0.07f;
static constexpr float NLL_MAX   = 13.815511f;    // -log(1e-6)
static constexpr float NLL_MIN   = 1.0000005e-6f; // -log(1-1e-6)

// Workspace layout (float offsets)
static constexpr size_t DOTSZ      = (size_t)BB * LL * SS;   // 8388608
static constexpr size_t OFF_LSER   = DOTSZ;                  // B*L
static constexpr size_t OFF_S2RAW  = DOTSZ + 8192;           // B*L
static constexpr size_t OFF_LSEC   = DOTSZ + 16384;          // B*S
static constexpr size_t OFF_S1RAW  = DOTSZ + 24576;          // B*S
static constexpr size_t OFF_SHARP2 = DOTSZ + 32768;          // B*L
static constexpr int    LCH        = 16;                     // l-chunks for col stats
static constexpr size_t OFF_COLP   = DOTSZ + 40960;          // B*LCH*4*S = 524288
static constexpr size_t OFF_ACC    = OFF_COLP + (size_t)BB * LCH * 4 * SS; // B*6
static constexpr size_t OFF_ACCCL  = OFF_ACC + 48;           // 2
static constexpr size_t OFF_QN     = OFF_ACC + 64;           // 8*128 normalized q_sel

// Output layout (floats): sharp1[8192], cl_pos_save[1024], total, geo_pos, geo_neg, loss_sharp, loss_cl
static constexpr int OUT_CLSAVE = 8192;
static constexpr int OUT_SCAL   = 9216;

typedef __bf16 bf16x8 __attribute__((ext_vector_type(8)));
typedef float  floatx4 __attribute__((ext_vector_type(4)));

// Split fp32 into bf16 hi + bf16 lo (RNE). x - float(hi) is Sterbenz-exact.
__device__ __forceinline__ void split_bf16(float x, short& hi, short& lo) {
    unsigned u = __builtin_bit_cast(unsigned, x);
    unsigned r = (u + 0x7FFFu + ((u >> 16) & 1u)) & 0xFFFF0000u;
    hi = (short)(r >> 16);
    float res = x - __builtin_bit_cast(float, r);
    unsigned u2 = __builtin_bit_cast(unsigned, res);
    lo = (short)((u2 + 0x7FFFu + ((u2 >> 16) & 1u)) >> 16);
}

// ---------------- Prep: zero accumulators, normalize q_sel, write cl_pos_save ----------------
__global__ __launch_bounds__(512) void prep(const float* __restrict__ q_cl,
                                            const float* __restrict__ cl_pos,
                                            const int* __restrict__ idx,
                                            float* __restrict__ out, float* __restrict__ ws) {
    int tid = threadIdx.x;
    if (tid < 50) ws[OFF_ACC + tid] = 0.0f;   // 48 geo acc + 2 contrast acc
    int n = tid >> 6, lane = tid & 63;
    int in = idx[n];
    const float* q = q_cl + ((size_t)(n * PP + in)) * CC;
    float2 qv = *(const float2*)(q + 2 * lane);
    float ss = qv.x * qv.x + qv.y * qv.y;
    for (int o = 32; o; o >>= 1) ss += __shfl_xor(ss, o);
    float inv = 1.0f / fmaxf(sqrtf(ss), 1e-12f);
    *(float2*)(ws + OFF_QN + n * 128 + 2 * lane) = make_float2(qv.x * inv, qv.y * inv);
    const float* cp = cl_pos + ((size_t)(n * PP + in)) * CC;
    float2 cv = *(const float2*)(cp + 2 * lane);
    *(float2*)(out + OUT_CLSAVE + n * 128 + 2 * lane) = cv;
}

// ---------------- GEMM (split-bf16 MFMA): dot[b,l,s] = sum_c q[b,l,c]*k[b,s,c] ----------------
__global__ __launch_bounds__(256) void gemm_dot(const float* __restrict__ A,
                                                const float* __restrict__ Bm,
                                                float* __restrict__ dot) {
    int b  = blockIdx.z;
    int l0 = blockIdx.y * 128;
    int s0 = blockIdx.x * 128;
    __shared__ short Ah[128 * 32];
    __shared__ short Al[128 * 32];
    __shared__ short Bh[128 * 32];
    __shared__ short Bl[128 * 32];

    int tid  = threadIdx.x;
    int lane = tid & 63;
    int w    = tid >> 6;           // wave 0..3
    int wr   = (w >> 1) * 64;      // wave row offset in tile
    int wc   = (w & 1) * 64;       // wave col offset
    int fl   = lane & 15;          // fragment lane index (m or n)
    int quad = lane >> 4;          // 0..3

    const float* Ab = A  + ((size_t)b * LL + l0) * CC;
    const float* Bb = Bm + ((size_t)b * SS + s0) * CC;

    floatx4 acc[4][4];
#pragma unroll
    for (int i = 0; i < 4; i++)
#pragma unroll
        for (int j = 0; j < 4; j++) acc[i][j] = (floatx4){0.f, 0.f, 0.f, 0.f};

    for (int c0 = 0; c0 < 128; c0 += 32) {
        if (c0) __syncthreads();
        // Stage A/B tiles (128 rows x 32 k) as bf16 hi/lo
#pragma unroll
        for (int rep = 0; rep < 4; rep++) {
            int slot = tid + rep * 256;            // 0..1023
            int row  = slot >> 3;
            int c4   = (slot & 7) * 4;
            float4 a4 = *(const float4*)(Ab + (size_t)row * CC + c0 + c4);
            float4 b4 = *(const float4*)(Bb + (size_t)row * CC + c0 + c4);
            short4 ah, al, bh, bl;
            split_bf16(a4.x, ah.x, al.x); split_bf16(a4.y, ah.y, al.y);
            split_bf16(a4.z, ah.z, al.z); split_bf16(a4.w, ah.w, al.w);
            split_bf16(b4.x, bh.x, bl.x); split_bf16(b4.y, bh.y, bl.y);
            split_bf16(b4.z, bh.z, bl.z); split_bf16(b4.w, bh.w, bl.w);
            int off = row * 32 + c4;
            *(short4*)(Ah + off) = ah; *(short4*)(Al + off) = al;
            *(short4*)(Bh + off) = bh; *(short4*)(Bl + off) = bl;
        }
        __syncthreads();

        // Load A fragments for this wave's 4 m-tiles
        bf16x8 afh[4], afl[4];
#pragma unroll
        for (int mt = 0; mt < 4; mt++) {
            int off = (wr + mt * 16 + fl) * 32 + quad * 8;
            afh[mt] = *reinterpret_cast<const bf16x8*>(Ah + off);
            afl[mt] = *reinterpret_cast<const bf16x8*>(Al + off);
        }
#pragma unroll
        for (int nt = 0; nt < 4; nt++) {
            int off = (wc + nt * 16 + fl) * 32 + quad * 8;
            bf16x8 bfh = *reinterpret_cast<const bf16x8*>(Bh + off);
            bf16x8 bfl = *reinterpret_cast<const bf16x8*>(Bl + off);
#pragma unroll
            for (int mt = 0; mt < 4; mt++) {
                acc[mt][nt] = __builtin_amdgcn_mfma_f32_16x16x32_bf16(afh[mt], bfh, acc[mt][nt], 0, 0, 0);
                acc[mt][nt] = __builtin_amdgcn_mfma_f32_16x16x32_bf16(afh[mt], bfl, acc[mt][nt], 0, 0, 0);
                acc[mt][nt] = __builtin_amdgcn_mfma_f32_16x16x32_bf16(afl[mt], bfh, acc[mt][nt], 0, 0, 0);
            }
        }
    }

    // Epilogue: C/D layout col=lane&15, row=quad*4+reg
    float* D = dot + ((size_t)b * LL + l0) * SS + s0;
#pragma unroll
    for (int mt = 0; mt < 4; mt++)
#pragma unroll
        for (int nt = 0; nt < 4; nt++) {
            int col = wc + nt * 16 + fl;
#pragma unroll
            for (int r = 0; r < 4; r++) {
                int row = wr + mt * 16 + quad * 4 + r;
                D[(size_t)row * SS + col] = acc[mt][nt][r];
            }
        }
}

// ---------------- Row stats: per (b,l): LSE over s of dot/T ; max/sum/sumsq of sim2 ----------------
__global__ __launch_bounds__(256) void row_stats(const float* __restrict__ dot, float* __restrict__ ws) {
    int row = blockIdx.x;  // b*L + l
    const float4* p = (const float4*)(dot + (size_t)row * SS);
    float4 v = p[threadIdx.x];
    float vals[4] = {v.x, v.y, v.z, v.w};
    float es = 0.0f, mx = -1e30f, sm = 0.0f, sq = 0.0f;
#pragma unroll
    for (int j = 0; j < 4; j++) {
        float d = vals[j];
        es += __expf(d * INV_T);
        float s2 = 0.5f + 0.5f * d;
        mx = fmaxf(mx, s2);
        sm += s2;
        sq += s2 * s2;
    }
    for (int o = 32; o; o >>= 1) {
        es += __shfl_xor(es, o);
        mx = fmaxf(mx, __shfl_xor(mx, o));
        sm += __shfl_xor(sm, o);
        sq += __shfl_xor(sq, o);
    }
    __shared__ float sb[4][4];
    int lane = threadIdx.x & 63, wid = threadIdx.x >> 6;
    if (!lane) { sb[0][wid] = es; sb[1][wid] = mx; sb[2][wid] = sm; sb[3][wid] = sq; }
    __syncthreads();
    if (threadIdx.x == 0) {
        es = sb[0][0] + sb[0][1] + sb[0][2] + sb[0][3];
        mx = fmaxf(fmaxf(sb[1][0], sb[1][1]), fmaxf(sb[1][2], sb[1][3]));
        sm = sb[2][0] + sb[2][1] + sb[2][2] + sb[2][3];
        sq = sb[3][0] + sb[3][1] + sb[3][2] + sb[3][3];
        ws[OFF_LSER + row] = __logf(es);
        float mean = sm * (1.0f / SS);
        float var = (sq - sm * sm * (1.0f / SS)) * (1.0f / (SS - 1));
        ws[OFF_S2RAW + row] = (mx - mean) / sqrtf(fmaxf(var, 1e-30f));
    }
}

// ---------------- Col stats partials over l-chunks of 64 ----------------
__global__ __launch_bounds__(256) void col_part(const float* __restrict__ dot, float* __restrict__ ws) {
    int b = blockIdx.z, lc = blockIdx.y, sc = blockIdx.x;
    int s = sc * 256 + threadIdx.x;
    const float* base = dot + ((size_t)(b * LL + lc * (LL / LCH))) * SS + s;
    float es = 0.0f, mx = -1e30f, sm = 0.0f, sq = 0.0f;
    for (int l = 0; l < LL / LCH; l++) {
        float d = base[(size_t)l * SS];
        es += __expf(d * INV_T);
        float s2 = 0.5f + 0.5f * d;
        mx = fmaxf(mx, s2);
        sm += s2;
        sq += s2 * s2;
    }
    float* cp = ws + OFF_COLP + ((size_t)(b * LCH + lc) * 4) * SS + s;
    cp[0] = es; cp[SS] = mx; cp[2 * SS] = sm; cp[3 * SS] = sq;
}

__global__ __launch_bounds__(256) void col_combine(float* __restrict__ ws) {
    int b = blockIdx.y, sc = blockIdx.x;
    int s = sc * 256 + threadIdx.x;
    float es = 0.0f, mx = -1e30f, sm = 0.0f, sq = 0.0f;
    for (int lc = 0; lc < LCH; lc++) {
        const float* cp = ws + OFF_COLP + ((size_t)(b * LCH + lc) * 4) * SS + s;
        es += cp[0];
        mx = fmaxf(mx, cp[SS]);
        sm += cp[2 * SS];
        sq += cp[3 * SS];
    }
    ws[OFF_LSEC + (size_t)b * SS + s] = __logf(es);
    float mean = sm * (1.0f / LL);
    float var = (sq - sm * sm * (1.0f / LL)) * (1.0f / (LL - 1));
    ws[OFF_S1RAW + (size_t)b * SS + s] = (mx - mean) / sqrtf(fmaxf(var, 1e-30f));
}

// ---------------- 16 softmaxes of length 1024: blocks 0..7 -> sharp1 (d_out), 8..15 -> sharp2 (ws) ----
__global__ __launch_bounds__(256) void softmax16(float* __restrict__ ws, float* __restrict__ out) {
    int q = blockIdx.x;
    int b = q & 7;
    const float* src = ws + ((q < 8) ? OFF_S1RAW : OFF_S2RAW) + (size_t)b * 1024;
    float* dst = (q < 8) ? (out + (size_t)b * 1024) : (ws + OFF_SHARP2 + (size_t)b * 1024);
    float4 v = ((const float4*)src)[threadIdx.x];
    int lane = threadIdx.x & 63, wid = threadIdx.x >> 6;
    __shared__ float sb[4];
    __shared__ float red;
    float mx = fmaxf(fmaxf(v.x, v.y), fmaxf(v.z, v.w));
    for (int o = 32; o; o >>= 1) mx = fmaxf(mx, __shfl_xor(mx, o));
    if (!lane) sb[wid] = mx;
    __syncthreads();
    if (threadIdx.x == 0) red = fmaxf(fmaxf(sb[0], sb[1]), fmaxf(sb[2], sb[3]));
    __syncthreads();
    mx = red;
    float e0 = __expf(v.x - mx), e1 = __expf(v.y - mx), e2 = __expf(v.z - mx), e3 = __expf(v.w - mx);
    float sm = e0 + e1 + e2 + e3;
    for (int o = 32; o; o >>= 1) sm += __shfl_xor(sm, o);
    __syncthreads();
    if (!lane) sb[wid] = sm;
    __syncthreads();
    if (threadIdx.x == 0) red = sb[0] + sb[1] + sb[2] + sb[3];
    __syncthreads();
    float inv = 1.0f / red;
    ((float4*)dst)[threadIdx.x] = make_float4(e0 * inv, e1 * inv, e2 * inv, e3 * inv);
}

// ---------------- Main elementwise loss pass (branchless) ----------------
__device__ __forceinline__ void proc_elem(float d, int lab, float lcj, float sh1j,
                                          float lr, float s2v,
                                          float& posg, float& negg, float& l1, float& l2,
                                          float& negs, float& pcf) {
    float t = lr + lcj - d * (2.0f * INV_T);   // -log(conf_geo)
    float isPos = (lab == 1) ? 1.0f : 0.0f;
    float isNeg = 1.0f - isPos;
    float tp   = fminf(fmaxf(t, NLL_MIN), NLL_MAX);
    float simc = fminf(fmaxf(fmaf(0.5f, d, 0.5f), EPS), ONE_M_EPS);
    float om   = fminf(fmaxf(fmaf(-0.5f, d, 0.5f), EPS), ONE_M_EPS);   // 1-simc exactly
    float nll2 = -__logf(simc);
    float cf   = fminf(fmaxf(__expf(-t), EPS), ONE_M_EPS);
    float nllg = -__logf(1.0f - cf);
    float nlls = -__logf(om);
    posg += isPos * tp;
    l1   += isPos * nll2 * sh1j;
    l2   += isPos * nll2 * s2v;
    pcf  += isPos;
    negg += isNeg * nllg;
    negs += isNeg * nlls;
}

__global__ __launch_bounds__(256) void main_loss(const float* __restrict__ dot,
                                                 const int* __restrict__ label,
                                                 const float* __restrict__ sharp1,
                                                 float* __restrict__ ws) {
    int b = blockIdx.y;
    int l0 = blockIdx.x * 4;
    int s = threadIdx.x * 4;
    float4 lc4 = *(const float4*)(ws + OFF_LSEC + (size_t)b * 1024 + s);
    float4 sh1 = *(const float4*)(sharp1 + (size_t)b * 1024 + s);
    const float* lser = ws + OFF_LSER + (size_t)b * 1024;
    const float* sh2  = ws + OFF_SHARP2 + (size_t)b * 1024;
    float posg = 0, negg = 0, l1 = 0, l2 = 0, negs = 0, pcf = 0;
#pragma unroll
    for (int r = 0; r < 4; r++) {
        int l = l0 + r;
        float lr  = lser[l];
        float s2v = sh2[l];
        size_t base = ((size_t)(b * 1024 + l)) * 1024 + s;
        float4 d4 = *(const float4*)(dot + base);
        int4  lb  = *(const int4*)(label + base);
        proc_elem(d4.x, lb.x, lc4.x, sh1.x, lr, s2v, posg, negg, l1, l2, negs, pcf);
        proc_elem(d4.y, lb.y, lc4.y, sh1.y, lr, s2v, posg, negg, l1, l2, negs, pcf);
        proc_elem(d4.z, lb.z, lc4.z, sh1.z, lr, s2v, posg, negg, l1, l2, negs, pcf);
        proc_elem(d4.w, lb.w, lc4.w, sh1.w, lr, s2v, posg, negg, l1, l2, negs, pcf);
    }
    float vals[6] = {posg, negg, l1, l2, negs, pcf};
    __shared__ float sb[6][4];
    int lane = threadIdx.x & 63, wid = threadIdx.x >> 6;
#pragma unroll
    for (int k = 0; k < 6; k++) {
        float v = vals[k];
        for (int o = 32; o; o >>= 1) v += __shfl_xor(v, o);
        if (!lane) sb[k][wid] = v;
    }
    __syncthreads();
    if (threadIdx.x < 6) {
        float r = sb[threadIdx.x][0] + sb[threadIdx.x][1] + sb[threadIdx.x][2] + sb[threadIdx.x][3];
        atomicAdd(ws + OFF_ACC + (size_t)b * 6 + threadIdx.x, r);
    }
}

// ---------------- Contrast loss: one wave per all_k row j ----------------
__global__ __launch_bounds__(256) void contrast(const float* __restrict__ cl_pos,
                                                const int* __restrict__ idx,
                                                float* __restrict__ ws) {
    int j = blockIdx.x * 4 + (threadIdx.x >> 6);
    int lane = threadIdx.x & 63;
    int m, p;
    if (j < NN) {
        m = j; p = idx[j];                 // all_k[j<N] = cl_pos[j, idx[j]]
    } else {
        int jj = j - NN;
        m = jj / (PP - 1);
        p = 1 + (jj - m * (PP - 1));
        if (p == idx[m]) p = 0;            // swapped: position idx[m] holds original row 0
    }
    const float* k = cl_pos + ((size_t)(m * PP + p)) * CC;
    float2 kv = *(const float2*)(k + 2 * lane);
    float ksq = kv.x * kv.x + kv.y * kv.y;
    for (int o = 32; o; o >>= 1) ksq += __shfl_xor(ksq, o);
    float invkn = 1.0f / fmaxf(sqrtf(ksq), 1e-12f);
    float pos = 0.0f, neg = 0.0f;
    if (j < NN) {
        const float2 qv = *(const float2*)(ws + OFF_QN + j * 128 + 2 * lane);
        float dt = qv.x * kv.x + qv.y * kv.y;
        for (int o = 32; o; o >>= 1) dt += __shfl_xor(dt, o);
        float sim = fminf(fmaxf(fmaf(0.5f * invkn, dt, 0.5f), EPS), ONE_M_EPS);
        pos = -__logf(sim);
    } else {
#pragma unroll
        for (int n = 0; n < NN; n++) {
            const float2 qv = *(const float2*)(ws + OFF_QN + n * 128 + 2 * lane);
            float dt = qv.x * kv.x + qv.y * kv.y;
            for (int o = 32; o; o >>= 1) dt += __shfl_xor(dt, o);
            float om = fminf(fmaxf(fmaf(-0.5f * invkn, dt, 0.5f), EPS), ONE_M_EPS); // 1-sim
            neg -= __logf(om);
        }
    }
    __shared__ float sb[2][4];
    int w = threadIdx.x >> 6;
    if (!lane) { sb[0][w] = pos; sb[1][w] = neg; }
    __syncthreads();
    if (threadIdx.x == 0) {
        float ps = sb[0][0] + sb[0][1] + sb[0][2] + sb[0][3];
        float ng = sb[1][0] + sb[1][1] + sb[1][2] + sb[1][3];
        if (ps != 0.0f) atomicAdd(ws + OFF_ACCCL + 0, ps);
        if (ng != 0.0f) atomicAdd(ws + OFF_ACCCL + 1, ng);
    }
}

// ---------------- Final scalar combine ----------------
__global__ void finalize(float* __restrict__ out, const float* __restrict__ ws) {
    if (threadIdx.x != 0) return;
    float gp = 0, gn = 0, lsh = 0;
    for (int b = 0; b < 8; b++) {
        const float* a = ws + OFF_ACC + (size_t)b * 6;
        float pc = a[5];
        float nc = (float)((size_t)LL * SS) - pc;
        gp += a[0] / fmaxf(pc, 1.0f);
        gn += a[1] / fmaxf(nc, 1.0f);
        lsh += (a[2] + a[3]) * 0.5f + a[4] / fmaxf(nc, 1.0f);
    }
    gp *= 0.125f; gn *= 0.125f; lsh *= 0.125f;
    float lgeo = gp + gn;
    float lgw = (0.5f * lgeo + 0.5f * lsh) * 0.5f;
    float clp = ws[OFF_ACCCL + 0] / 8.0f;
    float cln = ws[OFF_ACCCL + 1] / (8.0f * 2040.0f);
    float lcl = (clp + cln) * 0.5f * 0.5f;
    out[OUT_SCAL + 0] = lgw + lcl;  // total
    out[OUT_SCAL + 1] = gp;         // geo_pos_loss
    out[OUT_SCAL + 2] = gn;         // geo_neg_loss
    out[OUT_SCAL + 3] = lsh;        // loss_sharp
    out[OUT_SCAL + 4] = lcl;        // loss_cl
}

extern "C" void kernel_launch(void* const* d_in, const int* in_sizes, int n_in,
                              void* d_out, int out_size, void* d_ws, size_t ws_size,
                              hipStream_t stream) {
    const float* q_geo   = (const float*)d_in[0];
    const float* q_cl    = (const float*)d_in[1];
    const float* geo_pos = (const float*)d_in[2];
    const float* cl_pos  = (const float*)d_in[3];
    const int*   label   = (const int*)d_in[4];
    const int*   idx     = (const int*)d_in[5];
    float* out = (float*)d_out;
    float* ws  = (float*)d_ws;
    float* dot = ws;

    prep<<<dim3(1), dim3(512), 0, stream>>>(q_cl, cl_pos, idx, out, ws);
    gemm_dot<<<dim3(8, 8, 8), dim3(256), 0, stream>>>(q_geo, geo_pos, dot);
    row_stats<<<dim3(8192), dim3(256), 0, stream>>>(dot, ws);
    col_part<<<dim3(4, LCH, 8), dim3(256), 0, stream>>>(dot, ws);
    col_combine<<<dim3(4, 8), dim3(256), 0, stream>>>(ws);
    softmax16<<<dim3(16), dim3(256), 0, stream>>>(ws, out);
    main_loss<<<dim3(256, 8), dim3(256), 0, stream>>>(dot, label, out, ws);
    contrast<<<dim3(512), dim3(256), 0, stream>>>(cl_pos, idx, ws);
    finalize<<<dim3(1), dim3(64), 0, stream>>>(out, ws);
}

// Round 4
// 167.537 us; speedup vs baseline: 2.1418x; 1.0110x over previous
//
#include <hip/hip_runtime.h>
#include <math.h>

// Problem constants
#define BB 8
#define LL 1024
#define SS 1024
#define CC 128
#define NN 8
#define PP 256

static constexpr float EPS       = 1e-6f;
static constexpr float ONE_M_EPS = 1.0f - 1e-6f;
static constexpr float INV_T     = 1.0f / 0.07f;
static constexpr float NLL_MAX   = 13.815511f;    // -log(1e-6)
static constexpr float NLL_MIN   = 1.0000005e-6f; // -log(1-1e-6)

// Workspace layout (float offsets)
static constexpr size_t DOTSZ      = (size_t)BB * LL * SS;   // 8388608
static constexpr size_t OFF_LSER   = DOTSZ;                  // B*L
static constexpr size_t OFF_S2RAW  = DOTSZ + 8192;           // B*L
static constexpr size_t OFF_LSEC   = DOTSZ + 16384;          // B*S
static constexpr size_t OFF_S1RAW  = DOTSZ + 24576;          // B*S
static constexpr size_t OFF_SHARP2 = DOTSZ + 32768;          // B*L
static constexpr size_t OFF_RP     = DOTSZ + 40960;          // rowpart: 8*8*1024*4 = 262144
static constexpr size_t OFF_CP     = OFF_RP + 262144;        // colpart: 262144
static constexpr size_t OFF_ACC    = OFF_RP + 524288;        // B*6
static constexpr size_t OFF_ACCCL  = OFF_ACC + 48;           // 2
static constexpr size_t OFF_QN     = OFF_ACC + 64;           // 8*128 normalized q_sel

// Output layout (floats): sharp1[8192], cl_pos_save[1024], total, geo_pos, geo_neg, loss_sharp, loss_cl
static constexpr int OUT_CLSAVE = 8192;
static constexpr int OUT_SCAL   = 9216;

typedef __bf16 bf16x8 __attribute__((ext_vector_type(8)));
typedef float  floatx4 __attribute__((ext_vector_type(4)));

// LDS stride for staged tiles: 40 shorts = 80 B. Keeps ds_read_b128 16B-aligned
// (quad*16 offsets) and bank stride 20 -> worst-case 2-way conflict (free).
#define LSTR 40

// Split fp32 into bf16 hi + bf16 lo (RNE). x - float(hi) is exact.
__device__ __forceinline__ void split_bf16(float x, short& hi, short& lo) {
    unsigned u = __builtin_bit_cast(unsigned, x);
    unsigned r = (u + 0x7FFFu + ((u >> 16) & 1u)) & 0xFFFF0000u;
    hi = (short)(r >> 16);
    float res = x - __builtin_bit_cast(float, r);
    unsigned u2 = __builtin_bit_cast(unsigned, res);
    lo = (short)((u2 + 0x7FFFu + ((u2 >> 16) & 1u)) >> 16);
}

// ---------------- Prep: zero accumulators, normalize q_sel, write cl_pos_save ----------------
__global__ __launch_bounds__(512) void prep(const float* __restrict__ q_cl,
                                            const float* __restrict__ cl_pos,
                                            const int* __restrict__ idx,
                                            float* __restrict__ out, float* __restrict__ ws) {
    int tid = threadIdx.x;
    if (tid < 50) ws[OFF_ACC + tid] = 0.0f;   // 48 geo acc + 2 contrast acc
    int n = tid >> 6, lane = tid & 63;
    int in = idx[n];
    const float* q = q_cl + ((size_t)(n * PP + in)) * CC;
    float2 qv = *(const float2*)(q + 2 * lane);
    float ss = qv.x * qv.x + qv.y * qv.y;
    for (int o = 32; o; o >>= 1) ss += __shfl_xor(ss, o);
    float inv = 1.0f / fmaxf(sqrtf(ss), 1e-12f);
    *(float2*)(ws + OFF_QN + n * 128 + 2 * lane) = make_float2(qv.x * inv, qv.y * inv);
    const float* cp = cl_pos + ((size_t)(n * PP + in)) * CC;
    float2 cv = *(const float2*)(cp + 2 * lane);
    *(float2*)(out + OUT_CLSAVE + n * 128 + 2 * lane) = cv;
}

// ---------------- GEMM (split-bf16 MFMA) + fused row/col tile statistics ----------------
// dot[b,l,s] = sum_c q[b,l,c]*k[b,s,c]; also writes per-tile partials:
// rowpart[(b*8+st)*1024 + l][4] = {expsum, max, sum, sumsq} over this tile's 128 cols
// colpart[(b*8+lt)*1024 + s][4] = same over this tile's 128 rows
__global__ __launch_bounds__(256) void gemm_dot(const float* __restrict__ A,
                                                const float* __restrict__ Bm,
                                                float* __restrict__ dot,
                                                float* __restrict__ ws) {
    int b  = blockIdx.z;
    int lt = blockIdx.y;
    int st = blockIdx.x;
    int l0 = lt * 128;
    int s0 = st * 128;
    __shared__ short Ah[128 * LSTR];
    __shared__ short Al[128 * LSTR];
    __shared__ short Bh[128 * LSTR];
    __shared__ short Bl[128 * LSTR];
    __shared__ float rowLDS[2][128][4];   // [col-half][row][esum,max,sum,sumsq]
    __shared__ float colLDS[2][128][4];   // [row-half][col][...]

    int tid  = threadIdx.x;
    int lane = tid & 63;
    int w    = tid >> 6;           // wave 0..3
    int wr   = (w >> 1) * 64;      // wave row offset in tile
    int wc   = (w & 1) * 64;       // wave col offset
    int fl   = lane & 15;          // fragment lane index (m or n)
    int quad = lane >> 4;          // 0..3

    const float* Ab = A  + ((size_t)b * LL + l0) * CC;
    const float* Bb = Bm + ((size_t)b * SS + s0) * CC;

    floatx4 acc[4][4];
#pragma unroll
    for (int i = 0; i < 4; i++)
#pragma unroll
        for (int j = 0; j < 4; j++) acc[i][j] = (floatx4){0.f, 0.f, 0.f, 0.f};

    for (int c0 = 0; c0 < 128; c0 += 32) {
        if (c0) __syncthreads();
        // Stage A/B tiles (128 rows x 32 k) as bf16 hi/lo
#pragma unroll
        for (int rep = 0; rep < 4; rep++) {
            int slot = tid + rep * 256;            // 0..1023
            int row  = slot >> 3;
            int c4   = (slot & 7) * 4;
            float4 a4 = *(const float4*)(Ab + (size_t)row * CC + c0 + c4);
            float4 b4 = *(const float4*)(Bb + (size_t)row * CC + c0 + c4);
            short4 ah, al, bh, bl;
            split_bf16(a4.x, ah.x, al.x); split_bf16(a4.y, ah.y, al.y);
            split_bf16(a4.z, ah.z, al.z); split_bf16(a4.w, ah.w, al.w);
            split_bf16(b4.x, bh.x, bl.x); split_bf16(b4.y, bh.y, bl.y);
            split_bf16(b4.z, bh.z, bl.z); split_bf16(b4.w, bh.w, bl.w);
            int off = row * LSTR + c4;
            *(short4*)(Ah + off) = ah; *(short4*)(Al + off) = al;
            *(short4*)(Bh + off) = bh; *(short4*)(Bl + off) = bl;
        }
        __syncthreads();

        bf16x8 afh[4], afl[4];
#pragma unroll
        for (int mt = 0; mt < 4; mt++) {
            int off = (wr + mt * 16 + fl) * LSTR + quad * 8;
            afh[mt] = *reinterpret_cast<const bf16x8*>(Ah + off);
            afl[mt] = *reinterpret_cast<const bf16x8*>(Al + off);
        }
#pragma unroll
        for (int nt = 0; nt < 4; nt++) {
            int off = (wc + nt * 16 + fl) * LSTR + quad * 8;
            bf16x8 bfh = *reinterpret_cast<const bf16x8*>(Bh + off);
            bf16x8 bfl = *reinterpret_cast<const bf16x8*>(Bl + off);
#pragma unroll
            for (int mt = 0; mt < 4; mt++) {
                acc[mt][nt] = __builtin_amdgcn_mfma_f32_16x16x32_bf16(afh[mt], bfh, acc[mt][nt], 0, 0, 0);
                acc[mt][nt] = __builtin_amdgcn_mfma_f32_16x16x32_bf16(afh[mt], bfl, acc[mt][nt], 0, 0, 0);
                acc[mt][nt] = __builtin_amdgcn_mfma_f32_16x16x32_bf16(afl[mt], bfh, acc[mt][nt], 0, 0, 0);
            }
        }
    }

    // ---- Epilogue 1: write dot tile. C/D layout col=lane&15, row=quad*4+reg ----
    float* D = dot + ((size_t)b * LL + l0) * SS + s0;
#pragma unroll
    for (int mt = 0; mt < 4; mt++)
#pragma unroll
        for (int nt = 0; nt < 4; nt++) {
            int col = wc + nt * 16 + fl;
#pragma unroll
            for (int r = 0; r < 4; r++) {
                int row = wr + mt * 16 + quad * 4 + r;
                D[(size_t)row * SS + col] = acc[mt][nt][r];
            }
        }

    // ---- Epilogue 2: fused tile statistics ----
    float ces[4], cmx[4], csm[4], csq[4];
#pragma unroll
    for (int nt = 0; nt < 4; nt++) { ces[nt] = 0.f; cmx[nt] = -1e30f; csm[nt] = 0.f; csq[nt] = 0.f; }
#pragma unroll
    for (int mt = 0; mt < 4; mt++) {
#pragma unroll
        for (int r = 0; r < 4; r++) {
            float es = 0.f, mx = -1e30f, sm = 0.f, sq = 0.f;
#pragma unroll
            for (int nt = 0; nt < 4; nt++) {
                float d  = acc[mt][nt][r];
                float e  = __expf(d * INV_T);
                float s2 = fmaf(0.5f, d, 0.5f);
                es += e; mx = fmaxf(mx, s2); sm += s2; sq += s2 * s2;
                ces[nt] += e; cmx[nt] = fmaxf(cmx[nt], s2); csm[nt] += s2; csq[nt] += s2 * s2;
            }
            // reduce row partial across fl lanes (bits 0..3)
            for (int o = 1; o < 16; o <<= 1) {
                es += __shfl_xor(es, o);
                mx = fmaxf(mx, __shfl_xor(mx, o));
                sm += __shfl_xor(sm, o);
                sq += __shfl_xor(sq, o);
            }
            if (fl == 0) {
                int rib = wr + mt * 16 + quad * 4 + r;
                rowLDS[w & 1][rib][0] = es; rowLDS[w & 1][rib][1] = mx;
                rowLDS[w & 1][rib][2] = sm; rowLDS[w & 1][rib][3] = sq;
            }
        }
    }
#pragma unroll
    for (int nt = 0; nt < 4; nt++) {
        float es = ces[nt], mx = cmx[nt], sm = csm[nt], sq = csq[nt];
        // reduce col partial across quad lanes (bits 4,5)
        for (int o = 16; o < 64; o <<= 1) {
            es += __shfl_xor(es, o);
            mx = fmaxf(mx, __shfl_xor(mx, o));
            sm += __shfl_xor(sm, o);
            sq += __shfl_xor(sq, o);
        }
        if (quad == 0) {
            int cib = wc + nt * 16 + fl;
            colLDS[w >> 1][cib][0] = es; colLDS[w >> 1][cib][1] = mx;
            colLDS[w >> 1][cib][2] = sm; colLDS[w >> 1][cib][3] = sq;
        }
    }
    __syncthreads();
    if (tid < 128) {
        int rr = tid;
        float es = rowLDS[0][rr][0] + rowLDS[1][rr][0];
        float mx = fmaxf(rowLDS[0][rr][1], rowLDS[1][rr][1]);
        float sm = rowLDS[0][rr][2] + rowLDS[1][rr][2];
        float sq = rowLDS[0][rr][3] + rowLDS[1][rr][3];
        float4 v = make_float4(es, mx, sm, sq);
        *(float4*)(ws + OFF_RP + (((size_t)(b * 8 + st)) * 1024 + l0 + rr) * 4) = v;
    } else {
        int cc = tid - 128;
        float es = colLDS[0][cc][0] + colLDS[1][cc][0];
        float mx = fmaxf(colLDS[0][cc][1], colLDS[1][cc][1]);
        float sm = colLDS[0][cc][2] + colLDS[1][cc][2];
        float sq = colLDS[0][cc][3] + colLDS[1][cc][3];
        float4 v = make_float4(es, mx, sm, sq);
        *(float4*)(ws + OFF_CP + (((size_t)(b * 8 + lt)) * 1024 + s0 + cc) * 4) = v;
    }
}

// ---------------- Combine tile partials -> LSER/S2RAW (rows), LSEC/S1RAW (cols) ----------------
__global__ __launch_bounds__(256) void rc_combine(float* __restrict__ ws) {
    int g = (blockIdx.x & 31) * 256 + threadIdx.x;  // 0..8191
    bool docol = blockIdx.x >= 32;
    int b = g >> 10, i = g & 1023;
    const float* part = ws + (docol ? OFF_CP : OFF_RP);
    float es = 0.f, mx = -1e30f, sm = 0.f, sq = 0.f;
#pragma unroll
    for (int t = 0; t < 8; t++) {
        float4 v = *(const float4*)(part + (((size_t)(b * 8 + t)) * 1024 + i) * 4);
        es += v.x; mx = fmaxf(mx, v.y); sm += v.z; sq += v.w;
    }
    float mean = sm * (1.0f / 1024.0f);
    float var  = (sq - sm * sm * (1.0f / 1024.0f)) * (1.0f / 1023.0f);
    float zs   = (mx - mean) / sqrtf(fmaxf(var, 1e-30f));
    if (!docol) {
        ws[OFF_LSER + g]  = __logf(es);
        ws[OFF_S2RAW + g] = zs;
    } else {
        ws[OFF_LSEC + g]  = __logf(es);
        ws[OFF_S1RAW + g] = zs;
    }
}

// ---------------- 16 softmaxes of length 1024: blocks 0..7 -> sharp1 (d_out), 8..15 -> sharp2 (ws) ----
__global__ __launch_bounds__(256) void softmax16(float* __restrict__ ws, float* __restrict__ out) {
    int q = blockIdx.x;
    int b = q & 7;
    const float* src = ws + ((q < 8) ? OFF_S1RAW : OFF_S2RAW) + (size_t)b * 1024;
    float* dst = (q < 8) ? (out + (size_t)b * 1024) : (ws + OFF_SHARP2 + (size_t)b * 1024);
    float4 v = ((const float4*)src)[threadIdx.x];
    int lane = threadIdx.x & 63, wid = threadIdx.x >> 6;
    __shared__ float sb[4];
    __shared__ float red;
    float mx = fmaxf(fmaxf(v.x, v.y), fmaxf(v.z, v.w));
    for (int o = 32; o; o >>= 1) mx = fmaxf(mx, __shfl_xor(mx, o));
    if (!lane) sb[wid] = mx;
    __syncthreads();
    if (threadIdx.x == 0) red = fmaxf(fmaxf(sb[0], sb[1]), fmaxf(sb[2], sb[3]));
    __syncthreads();
    mx = red;
    float e0 = __expf(v.x - mx), e1 = __expf(v.y - mx), e2 = __expf(v.z - mx), e3 = __expf(v.w - mx);
    float sm = e0 + e1 + e2 + e3;
    for (int o = 32; o; o >>= 1) sm += __shfl_xor(sm, o);
    __syncthreads();
    if (!lane) sb[wid] = sm;
    __syncthreads();
    if (threadIdx.x == 0) red = sb[0] + sb[1] + sb[2] + sb[3];
    __syncthreads();
    float inv = 1.0f / red;
    ((float4*)dst)[threadIdx.x] = make_float4(e0 * inv, e1 * inv, e2 * inv, e3 * inv);
}

// ---------------- Main elementwise loss pass (branchless) ----------------
__device__ __forceinline__ void proc_elem(float d, int lab, float lcj, float sh1j,
                                          float lr, float s2v,
                                          float& posg, float& negg, float& l1, float& l2,
                                          float& negs, float& pcf) {
    float t = lr + lcj - d * (2.0f * INV_T);   // -log(conf_geo)
    float isPos = (lab == 1) ? 1.0f : 0.0f;
    float isNeg = 1.0f - isPos;
    float tp   = fminf(fmaxf(t, NLL_MIN), NLL_MAX);
    float simc = fminf(fmaxf(fmaf(0.5f, d, 0.5f), EPS), ONE_M_EPS);
    float om   = fminf(fmaxf(fmaf(-0.5f, d, 0.5f), EPS), ONE_M_EPS);   // 1-simc exactly
    float nll2 = -__logf(simc);
    float cf   = fminf(fmaxf(__expf(-t), EPS), ONE_M_EPS);
    float nllg = -__logf(1.0f - cf);
    float nlls = -__logf(om);
    posg += isPos * tp;
    l1   += isPos * nll2 * sh1j;
    l2   += isPos * nll2 * s2v;
    pcf  += isPos;
    negg += isNeg * nllg;
    negs += isNeg * nlls;
}

__global__ __launch_bounds__(256) void main_loss(const float* __restrict__ dot,
                                                 const int* __restrict__ label,
                                                 const float* __restrict__ sharp1,
                                                 float* __restrict__ ws) {
    int b = blockIdx.y;
    int l0 = blockIdx.x * 4;
    int s = threadIdx.x * 4;
    float4 lc4 = *(const float4*)(ws + OFF_LSEC + (size_t)b * 1024 + s);
    float4 sh1 = *(const float4*)(sharp1 + (size_t)b * 1024 + s);
    const float* lser = ws + OFF_LSER + (size_t)b * 1024;
    const float* sh2  = ws + OFF_SHARP2 + (size_t)b * 1024;
    float posg = 0, negg = 0, l1 = 0, l2 = 0, negs = 0, pcf = 0;
#pragma unroll
    for (int r = 0; r < 4; r++) {
        int l = l0 + r;
        float lr  = lser[l];
        float s2v = sh2[l];
        size_t base = ((size_t)(b * 1024 + l)) * 1024 + s;
        float4 d4 = *(const float4*)(dot + base);
        int4  lb  = *(const int4*)(label + base);
        proc_elem(d4.x, lb.x, lc4.x, sh1.x, lr, s2v, posg, negg, l1, l2, negs, pcf);
        proc_elem(d4.y, lb.y, lc4.y, sh1.y, lr, s2v, posg, negg, l1, l2, negs, pcf);
        proc_elem(d4.z, lb.z, lc4.z, sh1.z, lr, s2v, posg, negg, l1, l2, negs, pcf);
        proc_elem(d4.w, lb.w, lc4.w, sh1.w, lr, s2v, posg, negg, l1, l2, negs, pcf);
    }
    float vals[6] = {posg, negg, l1, l2, negs, pcf};
    __shared__ float sb[6][4];
    int lane = threadIdx.x & 63, wid = threadIdx.x >> 6;
#pragma unroll
    for (int k = 0; k < 6; k++) {
        float v = vals[k];
        for (int o = 32; o; o >>= 1) v += __shfl_xor(v, o);
        if (!lane) sb[k][wid] = v;
    }
    __syncthreads();
    if (threadIdx.x < 6) {
        float r = sb[threadIdx.x][0] + sb[threadIdx.x][1] + sb[threadIdx.x][2] + sb[threadIdx.x][3];
        atomicAdd(ws + OFF_ACC + (size_t)b * 6 + threadIdx.x, r);
    }
}

// ---------------- Contrast loss: one wave per all_k row j ----------------
__global__ __launch_bounds__(256) void contrast(const float* __restrict__ cl_pos,
                                                const int* __restrict__ idx,
                                                float* __restrict__ ws) {
    int j = blockIdx.x * 4 + (threadIdx.x >> 6);
    int lane = threadIdx.x & 63;
    int m, p;
    if (j < NN) {
        m = j; p = idx[j];                 // all_k[j<N] = cl_pos[j, idx[j]]
    } else {
        int jj = j - NN;
        m = jj / (PP - 1);
        p = 1 + (jj - m * (PP - 1));
        if (p == idx[m]) p = 0;            // swapped: position idx[m] holds original row 0
    }
    const float* k = cl_pos + ((size_t)(m * PP + p)) * CC;
    float2 kv = *(const float2*)(k + 2 * lane);
    float ksq = kv.x * kv.x + kv.y * kv.y;
    for (int o = 32; o; o >>= 1) ksq += __shfl_xor(ksq, o);
    float invkn = 1.0f / fmaxf(sqrtf(ksq), 1e-12f);
    float pos = 0.0f, neg = 0.0f;
    if (j < NN) {
        const float2 qv = *(const float2*)(ws + OFF_QN + j * 128 + 2 * lane);
        float dt = qv.x * kv.x + qv.y * kv.y;
        for (int o = 32; o; o >>= 1) dt += __shfl_xor(dt, o);
        float sim = fminf(fmaxf(fmaf(0.5f * invkn, dt, 0.5f), EPS), ONE_M_EPS);
        pos = -__logf(sim);
    } else {
#pragma unroll
        for (int n = 0; n < NN; n++) {
            const float2 qv = *(const float2*)(ws + OFF_QN + n * 128 + 2 * lane);
            float dt = qv.x * kv.x + qv.y * kv.y;
            for (int o = 32; o; o >>= 1) dt += __shfl_xor(dt, o);
            float om = fminf(fmaxf(fmaf(-0.5f * invkn, dt, 0.5f), EPS), ONE_M_EPS); // 1-sim
            neg -= __logf(om);
        }
    }
    __shared__ float sb[2][4];
    int w = threadIdx.x >> 6;
    if (!lane) { sb[0][w] = pos; sb[1][w] = neg; }
    __syncthreads();
    if (threadIdx.x == 0) {
        float ps = sb[0][0] + sb[0][1] + sb[0][2] + sb[0][3];
        float ng = sb[1][0] + sb[1][1] + sb[1][2] + sb[1][3];
        if (ps != 0.0f) atomicAdd(ws + OFF_ACCCL + 0, ps);
        if (ng != 0.0f) atomicAdd(ws + OFF_ACCCL + 1, ng);
    }
}

// ---------------- Final scalar combine ----------------
__global__ void finalize(float* __restrict__ out, const float* __restrict__ ws) {
    if (threadIdx.x != 0) return;
    float gp = 0, gn = 0, lsh = 0;
    for (int b = 0; b < 8; b++) {
        const float* a = ws + OFF_ACC + (size_t)b * 6;
        float pc = a[5];
        float nc = (float)((size_t)LL * SS) - pc;
        gp += a[0] / fmaxf(pc, 1.0f);
        gn += a[1] / fmaxf(nc, 1.0f);
        lsh += (a[2] + a[3]) * 0.5f + a[4] / fmaxf(nc, 1.0f);
    }
    gp *= 0.125f; gn *= 0.125f; lsh *= 0.125f;
    float lgeo = gp + gn;
    float lgw = (0.5f * lgeo + 0.5f * lsh) * 0.5f;
    float clp = ws[OFF_ACCCL + 0] / 8.0f;
    float cln = ws[OFF_ACCCL + 1] / (8.0f * 2040.0f);
    float lcl = (clp + cln) * 0.5f * 0.5f;
    out[OUT_SCAL + 0] = lgw + lcl;  // total
    out[OUT_SCAL + 1] = gp;         // geo_pos_loss
    out[OUT_SCAL + 2] = gn;         // geo_neg_loss
    out[OUT_SCAL + 3] = lsh;        // loss_sharp
    out[OUT_SCAL + 4] = lcl;        // loss_cl
}

extern "C" void kernel_launch(void* const* d_in, const int* in_sizes, int n_in,
                              void* d_out, int out_size, void* d_ws, size_t ws_size,
                              hipStream_t stream) {
    const float* q_geo   = (const float*)d_in[0];
    const float* q_cl    = (const float*)d_in[1];
    const float* geo_pos = (const float*)d_in[2];
    const float* cl_pos  = (const float*)d_in[3];
    const int*   label   = (const int*)d_in[4];
    const int*   idx     = (const int*)d_in[5];
    float* out = (float*)d_out;
    float* ws  = (float*)d_ws;
    float* dot = ws;

    prep<<<dim3(1), dim3(512), 0, stream>>>(q_cl, cl_pos, idx, out, ws);
    gemm_dot<<<dim3(8, 8, 8), dim3(256), 0, stream>>>(q_geo, geo_pos, dot, ws);
    rc_combine<<<dim3(64), dim3(256), 0, stream>>>(ws);
    softmax16<<<dim3(16), dim3(256), 0, stream>>>(ws, out);
    main_loss<<<dim3(256, 8), dim3(256), 0, stream>>>(dot, label, out, ws);
    contrast<<<dim3(512), dim3(256), 0, stream>>>(cl_pos, idx, ws);
    finalize<<<dim3(1), dim3(64), 0, stream>>>(out, ws);
}

// Round 5
// 163.677 us; speedup vs baseline: 2.1923x; 1.0236x over previous
//
#include <hip/hip_runtime.h>
#include <math.h>

// Problem constants
#define BB 8
#define LL 1024
#define SS 1024
#define CC 128
#define NN 8
#define PP 256

static constexpr float EPS       = 1e-6f;
static constexpr float ONE_M_EPS = 1.0f - 1e-6f;
static constexpr float INV_T     = 1.0f / 0.07f;
static constexpr float NLL_MAX   = 13.815511f;    // -log(1e-6)
static constexpr float NLL_MIN   = 1.0000005e-6f; // -log(1-1e-6)

// Workspace layout (float offsets)
static constexpr size_t DOTSZ      = (size_t)BB * LL * SS;   // 8388608
static constexpr size_t OFF_LSER   = DOTSZ;                  // B*L
static constexpr size_t OFF_S2RAW  = DOTSZ + 8192;           // B*L
static constexpr size_t OFF_LSEC   = DOTSZ + 16384;          // B*S
static constexpr size_t OFF_S1RAW  = DOTSZ + 24576;          // B*S
static constexpr size_t OFF_SHARP2 = DOTSZ + 32768;          // B*L
static constexpr size_t OFF_RP     = DOTSZ + 40960;          // rowpart: 8*16*1024*4 = 524288
static constexpr size_t OFF_CP     = OFF_RP + 524288;        // colpart: 524288
static constexpr size_t OFF_ACC    = OFF_CP + 524288;        // B*6
static constexpr size_t OFF_ACCCL  = OFF_ACC + 48;           // 2
static constexpr size_t OFF_QN     = OFF_ACC + 64;           // 8*128 normalized q_sel

// Output layout (floats): sharp1[8192], cl_pos_save[1024], total, geo_pos, geo_neg, loss_sharp, loss_cl
static constexpr int OUT_CLSAVE = 8192;
static constexpr int OUT_SCAL   = 9216;

typedef __bf16 bf16x8 __attribute__((ext_vector_type(8)));
typedef float  floatx4 __attribute__((ext_vector_type(4)));

__device__ __forceinline__ bf16x8 mkfrag(unsigned a, unsigned b, unsigned c, unsigned d) {
    uint4 t = make_uint4(a, b, c, d);
    return __builtin_bit_cast(bf16x8, t);
}

// Split 4 fp32 into packed bf16 hi pairs (RNE) + lo pairs (exact residual, truncated).
// hp0 = [bf16(x.x) | bf16(x.y)], etc. ~5 VALU/elem via v_perm_b32 packing.
__device__ __forceinline__ void split_f4(float4 x,
                                         unsigned& hp0, unsigned& hp1,
                                         unsigned& lp0, unsigned& lp1) {
    unsigned u0 = __builtin_bit_cast(unsigned, x.x);
    unsigned u1 = __builtin_bit_cast(unsigned, x.y);
    unsigned u2 = __builtin_bit_cast(unsigned, x.z);
    unsigned u3 = __builtin_bit_cast(unsigned, x.w);
    unsigned r0 = u0 + 0x7FFFu + ((u0 >> 16) & 1u);
    unsigned r1 = u1 + 0x7FFFu + ((u1 >> 16) & 1u);
    unsigned r2 = u2 + 0x7FFFu + ((u2 >> 16) & 1u);
    unsigned r3 = u3 + 0x7FFFu + ((u3 >> 16) & 1u);
    float s0 = x.x - __builtin_bit_cast(float, r0 & 0xFFFF0000u);
    float s1 = x.y - __builtin_bit_cast(float, r1 & 0xFFFF0000u);
    float s2 = x.z - __builtin_bit_cast(float, r2 & 0xFFFF0000u);
    float s3 = x.w - __builtin_bit_cast(float, r3 & 0xFFFF0000u);
    hp0 = __builtin_amdgcn_perm(r1, r0, 0x07060302u);
    hp1 = __builtin_amdgcn_perm(r3, r2, 0x07060302u);
    lp0 = __builtin_amdgcn_perm(__builtin_bit_cast(unsigned, s1),
                                __builtin_bit_cast(unsigned, s0), 0x07060302u);
    lp1 = __builtin_amdgcn_perm(__builtin_bit_cast(unsigned, s3),
                                __builtin_bit_cast(unsigned, s2), 0x07060302u);
}

// ---------------- Prep: zero accumulators, normalize q_sel, write cl_pos_save ----------------
__global__ __launch_bounds__(512) void prep(const float* __restrict__ q_cl,
                                            const float* __restrict__ cl_pos,
                                            const int* __restrict__ idx,
                                            float* __restrict__ out, float* __restrict__ ws) {
    int tid = threadIdx.x;
    if (tid < 50) ws[OFF_ACC + tid] = 0.0f;   // 48 geo acc + 2 contrast acc
    int n = tid >> 6, lane = tid & 63;
    int in = idx[n];
    const float* q = q_cl + ((size_t)(n * PP + in)) * CC;
    float2 qv = *(const float2*)(q + 2 * lane);
    float ss = qv.x * qv.x + qv.y * qv.y;
    for (int o = 32; o; o >>= 1) ss += __shfl_xor(ss, o);
    float inv = 1.0f / fmaxf(sqrtf(ss), 1e-12f);
    *(float2*)(ws + OFF_QN + n * 128 + 2 * lane) = make_float2(qv.x * inv, qv.y * inv);
    const float* cp = cl_pos + ((size_t)(n * PP + in)) * CC;
    float2 cv = *(const float2*)(cp + 2 * lane);
    *(float2*)(out + OUT_CLSAVE + n * 128 + 2 * lane) = cv;
}

// ---------------- GEMM: LDS-free, barrier-free. One wave per 64x64 output tile. ----------------
// dot[b,l,s] = sum_c q[b,l,c]*k[b,s,c] via split-bf16 MFMA (3 products).
// Fused per-wave row/col tile stats -> rowpart/colpart (16 tiles per row/col).
__global__ __launch_bounds__(256) void gemm_dot(const float* __restrict__ A,
                                                const float* __restrict__ Bm,
                                                float* __restrict__ dot,
                                                float* __restrict__ ws) {
    int tid  = threadIdx.x;
    int lane = tid & 63;
    int w    = tid >> 6;
    int t    = blockIdx.x * 4 + w;      // 0..2047
    int b    = t >> 8;
    int rem  = t & 255;
    int lt   = rem >> 4, st = rem & 15;
    int l0   = lt * 64, s0 = st * 64;
    int fl   = lane & 15;               // fragment row (m or n)
    int quad = lane >> 4;               // k-chunk / row-group

    const float* Ab = A  + ((size_t)b * LL + l0) * CC;
    const float* Bb = Bm + ((size_t)b * SS + s0) * CC;

    floatx4 acc[4][4];
#pragma unroll
    for (int i = 0; i < 4; i++)
#pragma unroll
        for (int j = 0; j < 4; j++) acc[i][j] = (floatx4){0.f, 0.f, 0.f, 0.f};

    for (int c0 = 0; c0 < 128; c0 += 32) {
        // Issue all 16 global loads for this k-step up front (coalesced 16 rows x 128B)
        float4 ax[4][2], bx[4][2];
#pragma unroll
        for (int mt = 0; mt < 4; mt++) {
            const float* p = Ab + (size_t)(mt * 16 + fl) * CC + c0 + quad * 8;
            ax[mt][0] = *(const float4*)p;
            ax[mt][1] = *(const float4*)(p + 4);
        }
#pragma unroll
        for (int nt = 0; nt < 4; nt++) {
            const float* p = Bb + (size_t)(nt * 16 + fl) * CC + c0 + quad * 8;
            bx[nt][0] = *(const float4*)p;
            bx[nt][1] = *(const float4*)(p + 4);
        }
        // Split A
        bf16x8 ah[4], al[4];
#pragma unroll
        for (int mt = 0; mt < 4; mt++) {
            unsigned h0, h1, h2, h3, q0, q1, q2, q3;
            split_f4(ax[mt][0], h0, h1, q0, q1);
            split_f4(ax[mt][1], h2, h3, q2, q3);
            ah[mt] = mkfrag(h0, h1, h2, h3);
            al[mt] = mkfrag(q0, q1, q2, q3);
        }
        // Split B + MFMA
#pragma unroll
        for (int nt = 0; nt < 4; nt++) {
            unsigned h0, h1, h2, h3, q0, q1, q2, q3;
            split_f4(bx[nt][0], h0, h1, q0, q1);
            split_f4(bx[nt][1], h2, h3, q2, q3);
            bf16x8 bh = mkfrag(h0, h1, h2, h3);
            bf16x8 bl = mkfrag(q0, q1, q2, q3);
#pragma unroll
            for (int mt = 0; mt < 4; mt++) {
                acc[mt][nt] = __builtin_amdgcn_mfma_f32_16x16x32_bf16(ah[mt], bh, acc[mt][nt], 0, 0, 0);
                acc[mt][nt] = __builtin_amdgcn_mfma_f32_16x16x32_bf16(ah[mt], bl, acc[mt][nt], 0, 0, 0);
                acc[mt][nt] = __builtin_amdgcn_mfma_f32_16x16x32_bf16(al[mt], bh, acc[mt][nt], 0, 0, 0);
            }
        }
    }

    // ---- Store dot tile. C/D layout: col=lane&15, row=quad*4+reg ----
    float* D = dot + ((size_t)b * LL + l0) * SS + s0;
#pragma unroll
    for (int mt = 0; mt < 4; mt++)
#pragma unroll
        for (int nt = 0; nt < 4; nt++) {
            int col = nt * 16 + fl;
#pragma unroll
            for (int r = 0; r < 4; r++) {
                int row = mt * 16 + quad * 4 + r;
                D[(size_t)row * SS + col] = acc[mt][nt][r];
            }
        }

    // ---- Fused wave-private tile statistics (no LDS, no barriers) ----
    float ces[4], cmx[4], csm[4], csq[4];
#pragma unroll
    for (int nt = 0; nt < 4; nt++) { ces[nt] = 0.f; cmx[nt] = -1e30f; csm[nt] = 0.f; csq[nt] = 0.f; }
#pragma unroll
    for (int mt = 0; mt < 4; mt++) {
#pragma unroll
        for (int r = 0; r < 4; r++) {
            float es = 0.f, mx = -1e30f, sm = 0.f, sq = 0.f;
#pragma unroll
            for (int nt = 0; nt < 4; nt++) {
                float d  = acc[mt][nt][r];
                float e  = __expf(d * INV_T);
                float s2 = fmaf(0.5f, d, 0.5f);
                es += e; mx = fmaxf(mx, s2); sm += s2; sq += s2 * s2;
                ces[nt] += e; cmx[nt] = fmaxf(cmx[nt], s2); csm[nt] += s2; csq[nt] += s2 * s2;
            }
            // reduce across fl lanes (bits 0..3); quad distinguishes rows
            for (int o = 1; o < 16; o <<= 1) {
                es += __shfl_xor(es, o);
                mx = fmaxf(mx, __shfl_xor(mx, o));
                sm += __shfl_xor(sm, o);
                sq += __shfl_xor(sq, o);
            }
            if (fl == 0) {
                int row = l0 + mt * 16 + quad * 4 + r;
                *(float4*)(ws + OFF_RP + (((size_t)(b * 16 + st)) * 1024 + row) * 4) =
                    make_float4(es, mx, sm, sq);
            }
        }
    }
#pragma unroll
    for (int nt = 0; nt < 4; nt++) {
        float es = ces[nt], mx = cmx[nt], sm = csm[nt], sq = csq[nt];
        // reduce across quad lanes (bits 4,5)
        for (int o = 16; o < 64; o <<= 1) {
            es += __shfl_xor(es, o);
            mx = fmaxf(mx, __shfl_xor(mx, o));
            sm += __shfl_xor(sm, o);
            sq += __shfl_xor(sq, o);
        }
        if (quad == 0) {
            int col = s0 + nt * 16 + fl;
            *(float4*)(ws + OFF_CP + (((size_t)(b * 16 + lt)) * 1024 + col) * 4) =
                make_float4(es, mx, sm, sq);
        }
    }
}

// ---------------- Combine tile partials -> LSER/S2RAW (rows), LSEC/S1RAW (cols) ----------------
__global__ __launch_bounds__(256) void rc_combine(float* __restrict__ ws) {
    int g = (blockIdx.x & 31) * 256 + threadIdx.x;  // 0..8191
    bool docol = blockIdx.x >= 32;
    int b = g >> 10, i = g & 1023;
    const float* part = ws + (docol ? OFF_CP : OFF_RP);
    float es = 0.f, mx = -1e30f, sm = 0.f, sq = 0.f;
#pragma unroll
    for (int t = 0; t < 16; t++) {
        float4 v = *(const float4*)(part + (((size_t)(b * 16 + t)) * 1024 + i) * 4);
        es += v.x; mx = fmaxf(mx, v.y); sm += v.z; sq += v.w;
    }
    float mean = sm * (1.0f / 1024.0f);
    float var  = (sq - sm * sm * (1.0f / 1024.0f)) * (1.0f / 1023.0f);
    float zs   = (mx - mean) / sqrtf(fmaxf(var, 1e-30f));
    if (!docol) {
        ws[OFF_LSER + g]  = __logf(es);
        ws[OFF_S2RAW + g] = zs;
    } else {
        ws[OFF_LSEC + g]  = __logf(es);
        ws[OFF_S1RAW + g] = zs;
    }
}

// ---------------- 16 softmaxes of length 1024: blocks 0..7 -> sharp1 (d_out), 8..15 -> sharp2 (ws) ----
__global__ __launch_bounds__(256) void softmax16(float* __restrict__ ws, float* __restrict__ out) {
    int q = blockIdx.x;
    int b = q & 7;
    const float* src = ws + ((q < 8) ? OFF_S1RAW : OFF_S2RAW) + (size_t)b * 1024;
    float* dst = (q < 8) ? (out + (size_t)b * 1024) : (ws + OFF_SHARP2 + (size_t)b * 1024);
    float4 v = ((const float4*)src)[threadIdx.x];
    int lane = threadIdx.x & 63, wid = threadIdx.x >> 6;
    __shared__ float sb[4];
    __shared__ float red;
    float mx = fmaxf(fmaxf(v.x, v.y), fmaxf(v.z, v.w));
    for (int o = 32; o; o >>= 1) mx = fmaxf(mx, __shfl_xor(mx, o));
    if (!lane) sb[wid] = mx;
    __syncthreads();
    if (threadIdx.x == 0) red = fmaxf(fmaxf(sb[0], sb[1]), fmaxf(sb[2], sb[3]));
    __syncthreads();
    mx = red;
    float e0 = __expf(v.x - mx), e1 = __expf(v.y - mx), e2 = __expf(v.z - mx), e3 = __expf(v.w - mx);
    float sm = e0 + e1 + e2 + e3;
    for (int o = 32; o; o >>= 1) sm += __shfl_xor(sm, o);
    __syncthreads();
    if (!lane) sb[wid] = sm;
    __syncthreads();
    if (threadIdx.x == 0) red = sb[0] + sb[1] + sb[2] + sb[3];
    __syncthreads();
    float inv = 1.0f / red;
    ((float4*)dst)[threadIdx.x] = make_float4(e0 * inv, e1 * inv, e2 * inv, e3 * inv);
}

// ---------------- Main elementwise loss pass (branchless) ----------------
__device__ __forceinline__ void proc_elem(float d, int lab, float lcj, float sh1j,
                                          float lr, float s2v,
                                          float& posg, float& negg, float& l1, float& l2,
                                          float& negs, float& pcf) {
    float t = lr + lcj - d * (2.0f * INV_T);   // -log(conf_geo)
    float isPos = (lab == 1) ? 1.0f : 0.0f;
    float isNeg = 1.0f - isPos;
    float tp   = fminf(fmaxf(t, NLL_MIN), NLL_MAX);
    float simc = fminf(fmaxf(fmaf(0.5f, d, 0.5f), EPS), ONE_M_EPS);
    float om   = fminf(fmaxf(fmaf(-0.5f, d, 0.5f), EPS), ONE_M_EPS);   // 1-simc exactly
    float nll2 = -__logf(simc);
    float cf   = fminf(fmaxf(__expf(-t), EPS), ONE_M_EPS);
    float nllg = -__logf(1.0f - cf);
    float nlls = -__logf(om);
    posg += isPos * tp;
    l1   += isPos * nll2 * sh1j;
    l2   += isPos * nll2 * s2v;
    pcf  += isPos;
    negg += isNeg * nllg;
    negs += isNeg * nlls;
}

__global__ __launch_bounds__(256) void main_loss(const float* __restrict__ dot,
                                                 const int* __restrict__ label,
                                                 const float* __restrict__ sharp1,
                                                 float* __restrict__ ws) {
    int b = blockIdx.y;
    int l0 = blockIdx.x * 4;
    int s = threadIdx.x * 4;
    float4 lc4 = *(const float4*)(ws + OFF_LSEC + (size_t)b * 1024 + s);
    float4 sh1 = *(const float4*)(sharp1 + (size_t)b * 1024 + s);
    const float* lser = ws + OFF_LSER + (size_t)b * 1024;
    const float* sh2  = ws + OFF_SHARP2 + (size_t)b * 1024;
    float posg = 0, negg = 0, l1 = 0, l2 = 0, negs = 0, pcf = 0;
#pragma unroll
    for (int r = 0; r < 4; r++) {
        int l = l0 + r;
        float lr  = lser[l];
        float s2v = sh2[l];
        size_t base = ((size_t)(b * 1024 + l)) * 1024 + s;
        float4 d4 = *(const float4*)(dot + base);
        int4  lb  = *(const int4*)(label + base);
        proc_elem(d4.x, lb.x, lc4.x, sh1.x, lr, s2v, posg, negg, l1, l2, negs, pcf);
        proc_elem(d4.y, lb.y, lc4.y, sh1.y, lr, s2v, posg, negg, l1, l2, negs, pcf);
        proc_elem(d4.z, lb.z, lc4.z, sh1.z, lr, s2v, posg, negg, l1, l2, negs, pcf);
        proc_elem(d4.w, lb.w, lc4.w, sh1.w, lr, s2v, posg, negg, l1, l2, negs, pcf);
    }
    float vals[6] = {posg, negg, l1, l2, negs, pcf};
    __shared__ float sb[6][4];
    int lane = threadIdx.x & 63, wid = threadIdx.x >> 6;
#pragma unroll
    for (int k = 0; k < 6; k++) {
        float v = vals[k];
        for (int o = 32; o; o >>= 1) v += __shfl_xor(v, o);
        if (!lane) sb[k][wid] = v;
    }
    __syncthreads();
    if (threadIdx.x < 6) {
        float r = sb[threadIdx.x][0] + sb[threadIdx.x][1] + sb[threadIdx.x][2] + sb[threadIdx.x][3];
        atomicAdd(ws + OFF_ACC + (size_t)b * 6 + threadIdx.x, r);
    }
}

// ---------------- Contrast loss: one wave per all_k row j ----------------
__global__ __launch_bounds__(256) void contrast(const float* __restrict__ cl_pos,
                                                const int* __restrict__ idx,
                                                float* __restrict__ ws) {
    int j = blockIdx.x * 4 + (threadIdx.x >> 6);
    int lane = threadIdx.x & 63;
    int m, p;
    if (j < NN) {
        m = j; p = idx[j];                 // all_k[j<N] = cl_pos[j, idx[j]]
    } else {
        int jj = j - NN;
        m = jj / (PP - 1);
        p = 1 + (jj - m * (PP - 1));
        if (p == idx[m]) p = 0;            // swapped: position idx[m] holds original row 0
    }
    const float* k = cl_pos + ((size_t)(m * PP + p)) * CC;
    float2 kv = *(const float2*)(k + 2 * lane);
    float ksq = kv.x * kv.x + kv.y * kv.y;
    for (int o = 32; o; o >>= 1) ksq += __shfl_xor(ksq, o);
    float invkn = 1.0f / fmaxf(sqrtf(ksq), 1e-12f);
    float pos = 0.0f, neg = 0.0f;
    if (j < NN) {
        const float2 qv = *(const float2*)(ws + OFF_QN + j * 128 + 2 * lane);
        float dt = qv.x * kv.x + qv.y * kv.y;
        for (int o = 32; o; o >>= 1) dt += __shfl_xor(dt, o);
        float sim = fminf(fmaxf(fmaf(0.5f * invkn, dt, 0.5f), EPS), ONE_M_EPS);
        pos = -__logf(sim);
    } else {
#pragma unroll
        for (int n = 0; n < NN; n++) {
            const float2 qv = *(const float2*)(ws + OFF_QN + n * 128 + 2 * lane);
            float dt = qv.x * kv.x + qv.y * kv.y;
            for (int o = 32; o; o >>= 1) dt += __shfl_xor(dt, o);
            float om = fminf(fmaxf(fmaf(-0.5f * invkn, dt, 0.5f), EPS), ONE_M_EPS); // 1-sim
            neg -= __logf(om);
        }
    }
    __shared__ float sb[2][4];
    int w = threadIdx.x >> 6;
    if (!lane) { sb[0][w] = pos; sb[1][w] = neg; }
    __syncthreads();
    if (threadIdx.x == 0) {
        float ps = sb[0][0] + sb[0][1] + sb[0][2] + sb[0][3];
        float ng = sb[1][0] + sb[1][1] + sb[1][2] + sb[1][3];
        if (ps != 0.0f) atomicAdd(ws + OFF_ACCCL + 0, ps);
        if (ng != 0.0f) atomicAdd(ws + OFF_ACCCL + 1, ng);
    }
}

// ---------------- Final scalar combine ----------------
__global__ void finalize(float* __restrict__ out, const float* __restrict__ ws) {
    if (threadIdx.x != 0) return;
    float gp = 0, gn = 0, lsh = 0;
    for (int b = 0; b < 8; b++) {
        const float* a = ws + OFF_ACC + (size_t)b * 6;
        float pc = a[5];
        float nc = (float)((size_t)LL * SS) - pc;
        gp += a[0] / fmaxf(pc, 1.0f);
        gn += a[1] / fmaxf(nc, 1.0f);
        lsh += (a[2] + a[3]) * 0.5f + a[4] / fmaxf(nc, 1.0f);
    }
    gp *= 0.125f; gn *= 0.125f; lsh *= 0.125f;
    float lgeo = gp + gn;
    float lgw = (0.5f * lgeo + 0.5f * lsh) * 0.5f;
    float clp = ws[OFF_ACCCL + 0] / 8.0f;
    float cln = ws[OFF_ACCCL + 1] / (8.0f * 2040.0f);
    float lcl = (clp + cln) * 0.5f * 0.5f;
    out[OUT_SCAL + 0] = lgw + lcl;  // total
    out[OUT_SCAL + 1] = gp;         // geo_pos_loss
    out[OUT_SCAL + 2] = gn;         // geo_neg_loss
    out[OUT_SCAL + 3] = lsh;        // loss_sharp
    out[OUT_SCAL + 4] = lcl;        // loss_cl
}

extern "C" void kernel_launch(void* const* d_in, const int* in_sizes, int n_in,
                              void* d_out, int out_size, void* d_ws, size_t ws_size,
                              hipStream_t stream) {
    const float* q_geo   = (const float*)d_in[0];
    const float* q_cl    = (const float*)d_in[1];
    const float* geo_pos = (const float*)d_in[2];
    const float* cl_pos  = (const float*)d_in[3];
    const int*   label   = (const int*)d_in[4];
    const int*   idx     = (const int*)d_in[5];
    float* out = (float*)d_out;
    float* ws  = (float*)d_ws;
    float* dot = ws;

    prep<<<dim3(1), dim3(512), 0, stream>>>(q_cl, cl_pos, idx, out, ws);
    gemm_dot<<<dim3(512), dim3(256), 0, stream>>>(q_geo, geo_pos, dot, ws);
    rc_combine<<<dim3(64), dim3(256), 0, stream>>>(ws);
    softmax16<<<dim3(16), dim3(256), 0, stream>>>(ws, out);
    main_loss<<<dim3(256, 8), dim3(256), 0, stream>>>(dot, label, out, ws);
    contrast<<<dim3(512), dim3(256), 0, stream>>>(cl_pos, idx, ws);
    finalize<<<dim3(1), dim3(64), 0, stream>>>(out, ws);
}